// Round 1
// baseline (338.847 us; speedup 1.0000x reference)
//
#include <hip/hip_runtime.h>

typedef __bf16 bf16x8 __attribute__((ext_vector_type(8)));
typedef float f32x4 __attribute__((ext_vector_type(4)));
typedef short s16x8 __attribute__((ext_vector_type(8)));
typedef unsigned short u16;
typedef unsigned int u32;

#define S_LEN 4096
#define DMODEL 1024
#define NH 16
#define HD 64

static __device__ __forceinline__ u16 f2bf(float f) {
  union { float f; u32 u; } a; a.f = f;
  u32 r = (a.u + 0x7fffu + ((a.u >> 16) & 1u)) >> 16;
  return (u16)r;
}

static __device__ __forceinline__ f32x4 mfma16(bf16x8 a, bf16x8 b, f32x4 c) {
  return __builtin_amdgcn_mfma_f32_16x16x32_bf16(a, b, c, 0, 0, 0);
}

static __device__ __forceinline__ void gload16(const void* g, void* l) {
  __builtin_amdgcn_global_load_lds((const __attribute__((address_space(1))) u32*)g,
                                   (__attribute__((address_space(3))) u32*)l, 16, 0, 0);
}

// ---------------- cast hidden fp32 -> bf16 ----------------
__global__ void cast_bf16_kernel(const float* __restrict__ x, u16* __restrict__ y) {
  const int i = ((int)blockIdx.x * 256 + (int)threadIdx.x) * 4;
  const float4 v = *(const float4*)(x + i);
  uint2 o;
  o.x = (u32)f2bf(v.x) | ((u32)f2bf(v.y) << 16);
  o.y = (u32)f2bf(v.z) | ((u32)f2bf(v.w) << 16);
  *(uint2*)(y + i) = o;
}

// ---------------- transpose + cast: W (K x N) fp32 -> WT (N x K) bf16 ----------------
__global__ void transpose_cast(const float* __restrict__ W, u16* __restrict__ WT,
                               int K, int N) {
  __shared__ float tile[32][33];
  const int tx = threadIdx.x, ty = threadIdx.y;   // (32, 8)
  const int n0 = (int)blockIdx.x * 32, k0 = (int)blockIdx.y * 32;
#pragma unroll
  for (int i = 0; i < 4; ++i)
    tile[ty + 8 * i][tx] = W[(size_t)(k0 + ty + 8 * i) * N + n0 + tx];
  __syncthreads();
#pragma unroll
  for (int i = 0; i < 4; ++i)
    WT[(size_t)(n0 + ty + 8 * i) * K + k0 + tx] = f2bf(tile[tx][ty + 8 * i]);
}

// ---------------- 128x128 MFMA GEMM core, K=1024 ----------------
// MODE 0: C fp32 out.  MODE 1: QKV with fused RoPE epilogue.
template <int MODE>
__global__ __launch_bounds__(256, 2)
void gemm128(const u16* __restrict__ A, const u16* __restrict__ BT,
             const float* __restrict__ cosp, const float* __restrict__ sinp,
             u16* __restrict__ Qb, u16* __restrict__ Kb, u16* __restrict__ Vb,
             float* __restrict__ Cf) {
  __shared__ __align__(16) u16 As[128 * 32];
  __shared__ __align__(16) u16 Bs[128 * 32];
  const int t = (int)threadIdx.x;
  const int w = t >> 6;
  const int lane = t & 63;
  const int lr = lane & 15, lg = lane >> 4;
  const int m0 = (int)blockIdx.y * 128;
  const int n0 = (int)blockIdx.x * 128;
  const int wm = (w >> 1) * 64, wn = (w & 1) * 64;

  f32x4 acc[4][4] = {};

  const int srow = t >> 2;        // 0..63
  const int scol = (t & 3) * 8;   // u16 offset within 32-wide k chunk

  for (int k0 = 0; k0 < 1024; k0 += 32) {
#pragma unroll
    for (int i = 0; i < 2; ++i) {
      gload16(A + (size_t)(m0 + i * 64 + srow) * 1024 + k0 + scol, As + i * 2048 + t * 8);
      gload16(BT + (size_t)(n0 + i * 64 + srow) * 1024 + k0 + scol, Bs + i * 2048 + t * 8);
    }
    __syncthreads();
    bf16x8 af[4], bg[4];
#pragma unroll
    for (int mi = 0; mi < 4; ++mi)
      af[mi] = *(const bf16x8*)(As + (wm + mi * 16 + lr) * 32 + lg * 8);
#pragma unroll
    for (int ni = 0; ni < 4; ++ni)
      bg[ni] = *(const bf16x8*)(Bs + (wn + ni * 16 + lr) * 32 + lg * 8);
#pragma unroll
    for (int mi = 0; mi < 4; ++mi)
#pragma unroll
      for (int ni = 0; ni < 4; ++ni)
        acc[mi][ni] = mfma16(af[mi], bg[ni], acc[mi][ni]);
    __syncthreads();
  }

  const int nbase = n0 + wn;  // multiple of 64 (one head per wave N-tile)
#pragma unroll
  for (int mi = 0; mi < 4; ++mi) {
#pragma unroll
    for (int r = 0; r < 4; ++r) {
      const int m = m0 + wm + mi * 16 + lg * 4 + r;
      if (MODE == 0) {
#pragma unroll
        for (int ni = 0; ni < 4; ++ni)
          Cf[(size_t)m * 1024 + nbase + ni * 16 + lr] = acc[mi][ni][r];
      } else {
        if (nbase < 1280) {
          // RoPE for Q or K
          const float* cr = cosp + (size_t)m * 64;
          const float* sr = sinp + (size_t)m * 64;
          float o[4];
#pragma unroll
          for (int ni = 0; ni < 2; ++ni) {
            const int d1 = ni * 16 + lr, d2 = d1 + 32;
            const float x = acc[mi][ni][r], y = acc[mi][ni + 2][r];
            o[ni]     = x * cr[d1] - y * sr[d1];
            o[ni + 2] = y * cr[d2] + x * sr[d2];
          }
          if (nbase < 1024) {
            u16* dst = Qb + (size_t)m * 1024 + nbase;
#pragma unroll
            for (int ni = 0; ni < 4; ++ni) dst[ni * 16 + lr] = f2bf(o[ni]);
          } else {
            u16* dst = Kb + (size_t)m * 256 + (nbase - 1024);
#pragma unroll
            for (int ni = 0; ni < 4; ++ni) dst[ni * 16 + lr] = f2bf(o[ni]);
          }
        } else {
          u16* dst = Vb + (size_t)m * 256 + (nbase - 1280);
#pragma unroll
          for (int ni = 0; ni < 4; ++ni) dst[ni * 16 + lr] = f2bf(acc[mi][ni][r]);
        }
      }
    }
  }
}

// ---------------- flash attention with sentence mask ----------------
// grid (64 q-tiles, 16 heads), 256 threads = 4 waves x 16 q-rows
__global__ __launch_bounds__(256, 2)
void attn_kernel(const u16* __restrict__ Qb, const u16* __restrict__ Kb,
                 const u16* __restrict__ Vb, const int* __restrict__ spec,
                 const int* __restrict__ eosi, u16* __restrict__ Ob) {
  __shared__ __align__(16) u16 Ks[64][72];
  __shared__ __align__(16) u16 Vt[64][72];
  __shared__ __align__(16) u16 Pb[4][16][72];
  __shared__ int sp[64];

  const int qt = 63 - (int)blockIdx.x;  // heavy tiles first
  const int h = (int)blockIdx.y;
  const int kvh = h >> 2;
  const int t = (int)threadIdx.x;
  const int w = t >> 6;
  const int lane = t & 63;
  const int lr = lane & 15, lg = lane >> 4;
  const int q0 = qt * 64;
  const int qw = q0 + w * 16;

  bf16x8 aq[2];
  {
    const u16* qp = Qb + (size_t)(qw + lr) * 1024 + h * 64 + lg * 8;
    aq[0] = *(const bf16x8*)qp;
    aq[1] = *(const bf16x8*)(qp + 32);
  }
  int eos_r[4];
#pragma unroll
  for (int r = 0; r < 4; ++r) eos_r[r] = eosi[qw + lg * 4 + r];

  f32x4 acc[4] = {};
  float mrow[4] = {-1e30f, -1e30f, -1e30f, -1e30f};
  float lrow[4] = {};

  const int skr = t >> 3;           // K staging row 0..31
  const int sd0 = (t & 7) * 8;      // K staging d offset
  const int vk = t & 63;            // V staging: lane spans k -> conflict-free LDS writes
  const int vwd = (t >> 6) * 16;

  for (int kb = 0; kb <= qt; ++kb) {
    const int kbase = kb * 64;
    // stage K row-major (padded rows: frag reads hit all 32 banks)
#pragma unroll
    for (int i = 0; i < 2; ++i) {
      s16x8 kv = *(const s16x8*)(Kb + (size_t)(kbase + skr + i * 32) * 256 + kvh * 64 + sd0);
      *(s16x8*)&Ks[skr + i * 32][sd0] = kv;
    }
    // stage V transposed: Vt[d][k]
#pragma unroll
    for (int i = 0; i < 2; ++i) {
      const int d0 = vwd + i * 8;
      s16x8 vv = *(const s16x8*)(Vb + (size_t)(kbase + vk) * 256 + kvh * 64 + d0);
#pragma unroll
      for (int j = 0; j < 8; ++j) Vt[d0 + j][vk] = (u16)vv[j];
    }
    if (t < 64) sp[t] = spec[kbase + t];
    __syncthreads();

    // QK^T
    float sv[4][4];
#pragma unroll
    for (int kt = 0; kt < 4; ++kt) {
      f32x4 s = {};
#pragma unroll
      for (int c = 0; c < 2; ++c) {
        bf16x8 bk = *(const bf16x8*)&Ks[kt * 16 + lr][c * 32 + lg * 8];
        s = mfma16(aq[c], bk, s);
      }
      const int kg = kbase + kt * 16 + lr;
      const bool spk = sp[kt * 16 + lr] != 0;
#pragma unroll
      for (int r = 0; r < 4; ++r) {
        const int qg = qw + lg * 4 + r;
        const bool ok = (kg <= qg) && (spk || kg >= eos_r[r]);
        sv[kt][r] = ok ? s[r] * 0.125f : -1e9f;
      }
    }
    // online softmax (rows live in 16-lane groups)
    float sc[4];
#pragma unroll
    for (int r = 0; r < 4; ++r) {
      float mx = fmaxf(fmaxf(sv[0][r], sv[1][r]), fmaxf(sv[2][r], sv[3][r]));
      mx = fmaxf(mx, __shfl_xor(mx, 1));
      mx = fmaxf(mx, __shfl_xor(mx, 2));
      mx = fmaxf(mx, __shfl_xor(mx, 4));
      mx = fmaxf(mx, __shfl_xor(mx, 8));
      const float mn = fmaxf(mrow[r], mx);
      sc[r] = __expf(mrow[r] - mn);
      mrow[r] = mn;
      float rs = 0.f;
#pragma unroll
      for (int kt = 0; kt < 4; ++kt) {
        const float p = __expf(sv[kt][r] - mn);
        sv[kt][r] = p;
        rs += p;
      }
      rs += __shfl_xor(rs, 1);
      rs += __shfl_xor(rs, 2);
      rs += __shfl_xor(rs, 4);
      rs += __shfl_xor(rs, 8);
      lrow[r] = lrow[r] * sc[r] + rs;
    }
#pragma unroll
    for (int dt = 0; dt < 4; ++dt)
#pragma unroll
      for (int r = 0; r < 4; ++r) acc[dt][r] *= sc[r];
    // P -> wave-private LDS (row = local q, k-contiguous for A-frag)
#pragma unroll
    for (int kt = 0; kt < 4; ++kt)
#pragma unroll
      for (int r = 0; r < 4; ++r)
        Pb[w][lg * 4 + r][kt * 16 + lr] = f2bf(sv[kt][r]);
    // PV
#pragma unroll
    for (int dt = 0; dt < 4; ++dt) {
#pragma unroll
      for (int c = 0; c < 2; ++c) {
        bf16x8 ap = *(const bf16x8*)&Pb[w][lr][c * 32 + lg * 8];
        bf16x8 bv = *(const bf16x8*)&Vt[dt * 16 + lr][c * 32 + lg * 8];
        acc[dt] = mfma16(ap, bv, acc[dt]);
      }
    }
    __syncthreads();
  }
  // epilogue: divide by row sum, store bf16 (S, H*HD)
#pragma unroll
  for (int r = 0; r < 4; ++r) {
    const int qg = qw + lg * 4 + r;
    const float inv = 1.0f / lrow[r];
#pragma unroll
    for (int dt = 0; dt < 4; ++dt)
      Ob[(size_t)qg * 1024 + h * 64 + dt * 16 + lr] = f2bf(acc[dt][r] * inv);
  }
}

// ---------------- launch ----------------
extern "C" void kernel_launch(void* const* d_in, const int* in_sizes, int n_in,
                              void* d_out, int out_size, void* d_ws, size_t ws_size,
                              hipStream_t stream) {
  (void)in_sizes; (void)n_in; (void)out_size; (void)ws_size;
  const float* hidden = (const float*)d_in[0];
  const float* cosp   = (const float*)d_in[1];
  const float* sinp   = (const float*)d_in[2];
  const float* Wq     = (const float*)d_in[3];
  const float* Wk     = (const float*)d_in[4];
  const float* Wv     = (const float*)d_in[5];
  const float* Wo     = (const float*)d_in[6];
  const int* spec     = (const int*)d_in[7];
  const int* eosi     = (const int*)d_in[8];
  float* out = (float*)d_out;

  u16* ws = (u16*)d_ws;
  u16* hbf   = ws;                       // 4096*1024
  u16* wqkvT = hbf + 4194304;            // 1536*1024 (rows: Wq^T | Wk^T | Wv^T)
  u16* woT   = wqkvT + 1572864;          // 1024*1024
  u16* Qb    = woT + 1048576;            // 4096*1024
  u16* Kb    = Qb + 4194304;             // 4096*256
  u16* Vb    = Kb + 1048576;             // 4096*256
  u16* Ob    = Vb + 1048576;             // 4096*1024

  cast_bf16_kernel<<<dim3(4096), dim3(256), 0, stream>>>(hidden, hbf);
  transpose_cast<<<dim3(32, 32), dim3(32, 8), 0, stream>>>(Wq, wqkvT, 1024, 1024);
  transpose_cast<<<dim3(8, 32), dim3(32, 8), 0, stream>>>(Wk, wqkvT + 1024 * 1024, 1024, 256);
  transpose_cast<<<dim3(8, 32), dim3(32, 8), 0, stream>>>(Wv, wqkvT + 1280 * 1024, 1024, 256);
  transpose_cast<<<dim3(32, 32), dim3(32, 8), 0, stream>>>(Wo, woT, 1024, 1024);

  gemm128<1><<<dim3(12, 32), dim3(256), 0, stream>>>(hbf, wqkvT, cosp, sinp,
                                                     Qb, Kb, Vb, nullptr);
  attn_kernel<<<dim3(64, 16), dim3(256), 0, stream>>>(Qb, Kb, Vb, spec, eosi, Ob);
  gemm128<0><<<dim3(8, 32), dim3(256), 0, stream>>>(Ob, woT, nullptr, nullptr,
                                                    nullptr, nullptr, nullptr, out);
}

// Round 2
// 254.517 us; speedup vs baseline: 1.3313x; 1.3313x over previous
//
#include <hip/hip_runtime.h>

typedef __bf16 bf16x8 __attribute__((ext_vector_type(8)));
typedef float f32x4 __attribute__((ext_vector_type(4)));
typedef short s16x8 __attribute__((ext_vector_type(8)));
typedef short s16x4 __attribute__((ext_vector_type(4)));
typedef unsigned short u16;
typedef unsigned int u32;
typedef unsigned long long u64;

#define S_LEN 4096
#define DMODEL 1024
#define NH 16
#define HD 64

static __device__ __forceinline__ u16 f2bf(float f) {
  union { float f; u32 u; } a; a.f = f;
  u32 r = (a.u + 0x7fffu + ((a.u >> 16) & 1u)) >> 16;
  return (u16)r;
}

static __device__ __forceinline__ f32x4 mfma16(bf16x8 a, bf16x8 b, f32x4 c) {
  return __builtin_amdgcn_mfma_f32_16x16x32_bf16(a, b, c, 0, 0, 0);
}

static __device__ __forceinline__ f32x4 mfma16x16(s16x4 a, s16x4 b, f32x4 c) {
#if __has_builtin(__builtin_amdgcn_mfma_f32_16x16x16bf16_1k)
  return __builtin_amdgcn_mfma_f32_16x16x16bf16_1k(a, b, c, 0, 0, 0);
#else
  asm("v_mfma_f32_16x16x16_bf16 %0, %1, %2, %0" : "+v"(c) : "v"(a), "v"(b));
  return c;
#endif
}

static __device__ __forceinline__ void gload16(const void* g, void* l) {
  __builtin_amdgcn_global_load_lds((const __attribute__((address_space(1))) u32*)g,
                                   (__attribute__((address_space(3))) u32*)l, 16, 0, 0);
}

// ---------------- cast hidden fp32 -> bf16 ----------------
__global__ void cast_bf16_kernel(const float* __restrict__ x, u16* __restrict__ y) {
  const int i = ((int)blockIdx.x * 256 + (int)threadIdx.x) * 4;
  const float4 v = *(const float4*)(x + i);
  uint2 o;
  o.x = (u32)f2bf(v.x) | ((u32)f2bf(v.y) << 16);
  o.y = (u32)f2bf(v.z) | ((u32)f2bf(v.w) << 16);
  *(uint2*)(y + i) = o;
}

// ---------------- transpose + cast: W (K x N) fp32 -> WT (N x K) bf16 ----------------
__global__ void transpose_cast(const float* __restrict__ W, u16* __restrict__ WT,
                               int K, int N) {
  __shared__ float tile[32][33];
  const int tx = threadIdx.x, ty = threadIdx.y;   // (32, 8)
  const int n0 = (int)blockIdx.x * 32, k0 = (int)blockIdx.y * 32;
#pragma unroll
  for (int i = 0; i < 4; ++i)
    tile[ty + 8 * i][tx] = W[(size_t)(k0 + ty + 8 * i) * N + n0 + tx];
  __syncthreads();
#pragma unroll
  for (int i = 0; i < 4; ++i)
    WT[(size_t)(n0 + ty + 8 * i) * K + k0 + tx] = f2bf(tile[tx][ty + 8 * i]);
}

// ---------------- spec bitmask: 64 keys -> u64 ----------------
__global__ void specmask_kernel(const int* __restrict__ spec, u64* __restrict__ spb) {
  const int b = (int)blockIdx.x;
  const u64 m = __ballot(spec[b * 64 + (int)threadIdx.x] != 0);
  if (threadIdx.x == 0) spb[b] = m;
}

// ---------------- V transpose: Vb[s][kvh*64+d] -> Vtg[kvh*64+d][s] (swizzled) ----------------
__global__ void vtrans_kernel(const u16* __restrict__ Vb, u16* __restrict__ Vtg) {
  __shared__ u16 tile[64][65];
  const int s0 = (int)blockIdx.x * 64;
  const int kvh = (int)blockIdx.y;
  const int t = (int)threadIdx.x;
  const int r = t >> 2, c4 = (t & 3) * 16;
  *(s16x8*)&tile[r][c4]     = *(const s16x8*)(Vb + (size_t)(s0 + r) * 256 + kvh * 64 + c4);
  *(s16x8*)&tile[r][c4 + 8] = *(const s16x8*)(Vb + (size_t)(s0 + r) * 256 + kvh * 64 + c4 + 8);
  __syncthreads();
  const int d = t >> 2, sc = (t & 3) * 16;
  const int sw = (d & 7) << 3;
#pragma unroll
  for (int a = 0; a < 2; ++a) {
    s16x8 o;
#pragma unroll
    for (int j = 0; j < 8; ++j) o[j] = (short)tile[sc + a * 8 + j][d];
    *(s16x8*)(Vtg + (size_t)(kvh * 64 + d) * 4096 + s0 + ((sc + a * 8) ^ sw)) = o;
  }
}

// ---------------- 128x128 MFMA GEMM core, K=1024 ----------------
// MODE 0: C fp32 out.  MODE 1: QKV with fused RoPE epilogue (K written swizzled).
template <int MODE>
__global__ __launch_bounds__(256, 2)
void gemm128(const u16* __restrict__ A, const u16* __restrict__ BT,
             const float* __restrict__ cosp, const float* __restrict__ sinp,
             u16* __restrict__ Qb, u16* __restrict__ Kb, u16* __restrict__ Vb,
             float* __restrict__ Cf) {
  __shared__ __align__(16) u16 As[128 * 32];
  __shared__ __align__(16) u16 Bs[128 * 32];
  const int t = (int)threadIdx.x;
  const int w = t >> 6;
  const int lane = t & 63;
  const int lr = lane & 15, lg = lane >> 4;
  const int m0 = (int)blockIdx.y * 128;
  const int n0 = (int)blockIdx.x * 128;
  const int wm = (w >> 1) * 64, wn = (w & 1) * 64;

  f32x4 acc[4][4] = {};

  const int srow = t >> 2;        // 0..63
  const int scol = (t & 3) * 8;   // u16 offset within 32-wide k chunk

  for (int k0 = 0; k0 < 1024; k0 += 32) {
#pragma unroll
    for (int i = 0; i < 2; ++i) {
      gload16(A + (size_t)(m0 + i * 64 + srow) * 1024 + k0 + scol, As + i * 2048 + t * 8);
      gload16(BT + (size_t)(n0 + i * 64 + srow) * 1024 + k0 + scol, Bs + i * 2048 + t * 8);
    }
    __syncthreads();
    bf16x8 af[4], bg[4];
#pragma unroll
    for (int mi = 0; mi < 4; ++mi)
      af[mi] = *(const bf16x8*)(As + (wm + mi * 16 + lr) * 32 + lg * 8);
#pragma unroll
    for (int ni = 0; ni < 4; ++ni)
      bg[ni] = *(const bf16x8*)(Bs + (wn + ni * 16 + lr) * 32 + lg * 8);
#pragma unroll
    for (int mi = 0; mi < 4; ++mi)
#pragma unroll
      for (int ni = 0; ni < 4; ++ni)
        acc[mi][ni] = mfma16(af[mi], bg[ni], acc[mi][ni]);
    __syncthreads();
  }

  const int nbase = n0 + wn;  // multiple of 64 (one head per wave N-tile)
#pragma unroll
  for (int mi = 0; mi < 4; ++mi) {
#pragma unroll
    for (int r = 0; r < 4; ++r) {
      const int m = m0 + wm + mi * 16 + lg * 4 + r;
      if (MODE == 0) {
#pragma unroll
        for (int ni = 0; ni < 4; ++ni)
          Cf[(size_t)m * 1024 + nbase + ni * 16 + lr] = acc[mi][ni][r];
      } else {
        if (nbase < 1280) {
          // RoPE for Q or K
          const float* cr = cosp + (size_t)m * 64;
          const float* sr = sinp + (size_t)m * 64;
          float o[4];
#pragma unroll
          for (int ni = 0; ni < 2; ++ni) {
            const int d1 = ni * 16 + lr, d2 = d1 + 32;
            const float x = acc[mi][ni][r], y = acc[mi][ni + 2][r];
            o[ni]     = x * cr[d1] - y * sr[d1];
            o[ni + 2] = y * cr[d2] + x * sr[d2];
          }
          if (nbase < 1024) {
            u16* dst = Qb + (size_t)m * 1024 + nbase;
#pragma unroll
            for (int ni = 0; ni < 4; ++ni) dst[ni * 16 + lr] = f2bf(o[ni]);
          } else {
            u16* dst = Kb + (size_t)m * 256 + (nbase - 1024);
            const int sw = (m & 7) << 3;
#pragma unroll
            for (int ni = 0; ni < 4; ++ni) dst[(ni * 16 + lr) ^ sw] = f2bf(o[ni]);
          }
        } else {
          u16* dst = Vb + (size_t)m * 256 + (nbase - 1280);
#pragma unroll
          for (int ni = 0; ni < 4; ++ni) dst[ni * 16 + lr] = f2bf(acc[mi][ni][r]);
        }
      }
    }
  }
}

// ---------------- flash attention, swapped-QK^T, in-register P ----------------
// grid (64 q-tiles, 16 heads), 256 threads = 4 waves x 16 q-rows
__global__ __launch_bounds__(256, 4)
void attn_kernel(const u16* __restrict__ Qb, const u16* __restrict__ Kb,
                 const u16* __restrict__ Vtg, const u64* __restrict__ spb,
                 const int* __restrict__ eosi, u16* __restrict__ Ob) {
  __shared__ __align__(16) u16 lds[2][2][4096];  // [buf][K|Vt][64 rows x 64 elems]

  const int qt = 63 - (int)blockIdx.x;  // heavy tiles first
  const int h = (int)blockIdx.y;
  const int kvh = h >> 2;
  const int t = (int)threadIdx.x;
  const int w = t >> 6;
  const int lane = t & 63;
  const int lr = lane & 15, lg = lane >> 4;
  const int q0 = qt * 64;
  const int q = q0 + w * 16 + lr;       // this lane's q-row
  const int swl = (lr & 7) << 3;        // LDS read swizzle (elems)

  // Q fragment (B-frag of swapped QK): row q, d = c*32 + lg*8 + j
  bf16x8 aq[2];
  {
    const u16* qp = Qb + (size_t)q * 1024 + h * 64 + lg * 8;
    aq[0] = *(const bf16x8*)qp;
    aq[1] = *(const bf16x8*)(qp + 32);
  }
  const int eos_q = eosi[q];

  f32x4 acc[4] = {};      // acc[dt]: d = dt*16 + lg*4 + r, col q = lr
  float mrow = -3.0e38f;  // running max (log2 domain)
  float lrow = 0.0f;

  const int grow = t >> 3;        // staging row 0..31 (+32i)
  const int gcol = (t & 7) * 8;   // staging col (elems)

  auto STAGE = [&](int buf, int kbase) {
#pragma unroll
    for (int i = 0; i < 2; ++i) {
      gload16(Kb + (size_t)(kbase + i * 32 + grow) * 256 + kvh * 64 + gcol,
              &lds[buf][0][i * 2048 + t * 8]);
      gload16(Vtg + (size_t)(kvh * 64 + i * 32 + grow) * 4096 + kbase + gcol,
              &lds[buf][1][i * 2048 + t * 8]);
    }
  };

  STAGE(0, 0);
  __syncthreads();

  for (int kb = 0; kb <= qt; ++kb) {
    const int kbase = kb * 64;
    if (kb < qt) STAGE((kb + 1) & 1, kbase + 64);
    const u16* Kl = &lds[kb & 1][0][0];
    const u16* Vl = &lds[kb & 1][1][0];

    // swapped QK^T: st[kt] rows k = kbase + kt*16 + lg*4 + r, col q = lr
    f32x4 st[4];
#pragma unroll
    for (int kt = 0; kt < 4; ++kt) {
      f32x4 s = {};
#pragma unroll
      for (int c = 0; c < 2; ++c) {
        bf16x8 ak = *(const bf16x8*)(Kl + (kt * 16 + lr) * 64 + ((c * 32 + lg * 8) ^ swl));
        s = mfma16(ak, aq[c], s);
      }
      st[kt] = s;
    }

    // mask: causal & (k>=eos | special)
    const u64 spec = spb[kb];
    const int dq = q - kbase;
    const u64 causal = (dq >= 63) ? ~0ull : ((2ull << dq) - 1ull);
    const int de = eos_q - kbase;
    const u64 ge = (de <= 0) ? ~0ull : (de >= 64 ? 0ull : (~0ull << de));
    const u64 allowed = causal & (ge | spec);

    // scores -> log2 domain, masked
    float xs[16];
    float tmax = -3.0e38f;
#pragma unroll
    for (int kt = 0; kt < 4; ++kt) {
      const u32 bits = (u32)(allowed >> (kt * 16 + lg * 4)) & 0xFu;
#pragma unroll
      for (int r = 0; r < 4; ++r) {
        const float x = ((bits >> r) & 1u) ? st[kt][r] * 0.18033688011112042f : -3.0e38f;
        xs[kt * 4 + r] = x;
        tmax = fmaxf(tmax, x);
      }
    }
    tmax = fmaxf(tmax, __shfl_xor(tmax, 16));
    tmax = fmaxf(tmax, __shfl_xor(tmax, 32));
    const float mn = fmaxf(mrow, tmax);
    const float resc = exp2f(mrow - mn);
    mrow = mn;

    float rs = 0.0f;
    u32 pk[8];
#pragma unroll
    for (int i = 0; i < 16; i += 2) {
      const float p0 = exp2f(xs[i] - mn);
      const float p1 = exp2f(xs[i + 1] - mn);
      rs += p0 + p1;
      pk[i >> 1] = (u32)f2bf(p0) | ((u32)f2bf(p1) << 16);
    }
    rs += __shfl_xor(rs, 16);
    rs += __shfl_xor(rs, 32);
    lrow = lrow * resc + rs;

#pragma unroll
    for (int dt = 0; dt < 4; ++dt)
#pragma unroll
      for (int r = 0; r < 4; ++r) acc[dt][r] *= resc;

    // PV: per kt, B-frag = softmax quad (k = kt*16 + lg*4 + j) straight from regs
#pragma unroll
    for (int kt = 0; kt < 4; ++kt) {
      union { u32 u[2]; s16x4 v; } cv;
      cv.u[0] = pk[kt * 2]; cv.u[1] = pk[kt * 2 + 1];
      const int vo = (kt * 16 + lg * 4) ^ swl;
#pragma unroll
      for (int dt = 0; dt < 4; ++dt) {
        s16x4 av = *(const s16x4*)(Vl + (dt * 16 + lr) * 64 + vo);
        acc[dt] = mfma16x16(av, cv.v, acc[dt]);
      }
    }
    __syncthreads();
  }

  // epilogue: normalize, store bf16 (S, H*HD)
  const float inv = 1.0f / lrow;
#pragma unroll
  for (int dt = 0; dt < 4; ++dt) {
    const u32 w0 = (u32)f2bf(acc[dt][0] * inv) | ((u32)f2bf(acc[dt][1] * inv) << 16);
    const u32 w1 = (u32)f2bf(acc[dt][2] * inv) | ((u32)f2bf(acc[dt][3] * inv) << 16);
    u32* dst = (u32*)(Ob + (size_t)q * 1024 + h * 64 + dt * 16 + lg * 4);
    dst[0] = w0; dst[1] = w1;
  }
}

// ---------------- launch ----------------
extern "C" void kernel_launch(void* const* d_in, const int* in_sizes, int n_in,
                              void* d_out, int out_size, void* d_ws, size_t ws_size,
                              hipStream_t stream) {
  (void)in_sizes; (void)n_in; (void)out_size; (void)ws_size;
  const float* hidden = (const float*)d_in[0];
  const float* cosp   = (const float*)d_in[1];
  const float* sinp   = (const float*)d_in[2];
  const float* Wq     = (const float*)d_in[3];
  const float* Wk     = (const float*)d_in[4];
  const float* Wv     = (const float*)d_in[5];
  const float* Wo     = (const float*)d_in[6];
  const int* spec     = (const int*)d_in[7];
  const int* eosi     = (const int*)d_in[8];
  float* out = (float*)d_out;

  u16* ws = (u16*)d_ws;
  u16* hbf   = ws;                       // 4096*1024 (reused as Vtg/spb after QKV gemm)
  u16* wqkvT = hbf + 4194304;            // 1536*1024 (rows: Wq^T | Wk^T | Wv^T)
  u16* woT   = wqkvT + 1572864;          // 1024*1024
  u16* Qb    = woT + 1048576;            // 4096*1024
  u16* Kb    = Qb + 4194304;             // 4096*256 (swizzled within head block)
  u16* Vb    = Kb + 1048576;             // 4096*256
  u16* Ob    = Vb + 1048576;             // 4096*1024
  u16* Vtg   = hbf;                      // 4*64*4096 (transposed V, swizzled)
  u64* spb   = (u64*)(hbf + 2097152);    // 64 x u64

  cast_bf16_kernel<<<dim3(4096), dim3(256), 0, stream>>>(hidden, hbf);
  transpose_cast<<<dim3(32, 32), dim3(32, 8), 0, stream>>>(Wq, wqkvT, 1024, 1024);
  transpose_cast<<<dim3(8, 32), dim3(32, 8), 0, stream>>>(Wk, wqkvT + 1024 * 1024, 1024, 256);
  transpose_cast<<<dim3(8, 32), dim3(32, 8), 0, stream>>>(Wv, wqkvT + 1280 * 1024, 1024, 256);
  transpose_cast<<<dim3(32, 32), dim3(32, 8), 0, stream>>>(Wo, woT, 1024, 1024);

  gemm128<1><<<dim3(12, 32), dim3(256), 0, stream>>>(hbf, wqkvT, cosp, sinp,
                                                     Qb, Kb, Vb, nullptr);
  vtrans_kernel<<<dim3(64, 4), dim3(256), 0, stream>>>(Vb, Vtg);
  specmask_kernel<<<dim3(64), dim3(64), 0, stream>>>(spec, spb);
  attn_kernel<<<dim3(64, 16), dim3(256), 0, stream>>>(Qb, Kb, Vtg, spb, eosi, Ob);
  gemm128<0><<<dim3(8, 32), dim3(256), 0, stream>>>(Ob, woT, nullptr, nullptr,
                                                    nullptr, nullptr, nullptr, out);
}

// Round 3
// 122.221 us; speedup vs baseline: 2.7724x; 2.0824x over previous
//
#include <hip/hip_runtime.h>

typedef __bf16 bf16x8 __attribute__((ext_vector_type(8)));
typedef float f32x4 __attribute__((ext_vector_type(4)));
typedef short s16x8 __attribute__((ext_vector_type(8)));
typedef short s16x4 __attribute__((ext_vector_type(4)));
typedef unsigned short u16;
typedef unsigned int u32;
typedef unsigned long long u64;

#define S_LEN 4096
#define DMODEL 1024
#define NH 16
#define HD 64

static __device__ __forceinline__ u16 f2bf(float f) {
  union { float f; u32 u; } a; a.f = f;
  u32 r = (a.u + 0x7fffu + ((a.u >> 16) & 1u)) >> 16;
  return (u16)r;
}

static __device__ __forceinline__ f32x4 mfma16(bf16x8 a, bf16x8 b, f32x4 c) {
  return __builtin_amdgcn_mfma_f32_16x16x32_bf16(a, b, c, 0, 0, 0);
}

static __device__ __forceinline__ f32x4 mfma16x16(s16x4 a, s16x4 b, f32x4 c) {
#if __has_builtin(__builtin_amdgcn_mfma_f32_16x16x16bf16_1k)
  return __builtin_amdgcn_mfma_f32_16x16x16bf16_1k(a, b, c, 0, 0, 0);
#else
  asm("v_mfma_f32_16x16x16_bf16 %0, %1, %2, %0" : "+v"(c) : "v"(a), "v"(b));
  return c;
#endif
}

static __device__ __forceinline__ void gload16(const void* g, void* l) {
  __builtin_amdgcn_global_load_lds((const __attribute__((address_space(1))) u32*)g,
                                   (__attribute__((address_space(3))) u32*)l, 16, 0, 0);
}

// ---------------- cast hidden fp32 -> bf16 ----------------
__global__ void cast_bf16_kernel(const float* __restrict__ x, u16* __restrict__ y) {
  const int i = ((int)blockIdx.x * 256 + (int)threadIdx.x) * 4;
  const float4 v = *(const float4*)(x + i);
  uint2 o;
  o.x = (u32)f2bf(v.x) | ((u32)f2bf(v.y) << 16);
  o.y = (u32)f2bf(v.z) | ((u32)f2bf(v.w) << 16);
  *(uint2*)(y + i) = o;
}

// ---------------- transpose + cast: W (K x N) fp32 -> WT (N x K) bf16 ----------------
__global__ void transpose_cast(const float* __restrict__ W, u16* __restrict__ WT,
                               int K, int N) {
  __shared__ float tile[32][33];
  const int tx = threadIdx.x, ty = threadIdx.y;   // (32, 8)
  const int n0 = (int)blockIdx.x * 32, k0 = (int)blockIdx.y * 32;
#pragma unroll
  for (int i = 0; i < 4; ++i)
    tile[ty + 8 * i][tx] = W[(size_t)(k0 + ty + 8 * i) * N + n0 + tx];
  __syncthreads();
#pragma unroll
  for (int i = 0; i < 4; ++i)
    WT[(size_t)(n0 + ty + 8 * i) * K + k0 + tx] = f2bf(tile[tx][ty + 8 * i]);
}

// ---------------- spec bitmask: 64 keys -> u64 ----------------
__global__ void specmask_kernel(const int* __restrict__ spec, u64* __restrict__ spb) {
  const int b = (int)blockIdx.x;
  const u64 m = __ballot(spec[b * 64 + (int)threadIdx.x] != 0);
  if (threadIdx.x == 0) spb[b] = m;
}

// ---------------- gather special indices + per-tile prefix counts ----------------
__global__ void spec_gather_kernel(const int* __restrict__ spec, int* __restrict__ sidx,
                                   int* __restrict__ scount) {
  const int lane = (int)threadIdx.x;  // 64 threads (1 wave)
  int base = 0;
  for (int b = 0; b < 64; ++b) {
    const u64 m = __ballot(spec[b * 64 + lane] != 0);
    if (lane == 0) scount[b] = base;
    const int pre = __popcll(m & ((1ull << lane) - 1ull));
    if ((m >> lane) & 1ull) sidx[base + pre] = b * 64 + lane;
    base += __popcll(m);
  }
  if (lane == 0) scount[64] = base;
}

// ---------------- pack gathered special K rows / V^T cols (swizzled) ----------------
__global__ void spec_pack_kernel(const u16* __restrict__ Kb, const u16* __restrict__ Vb,
                                 const int* __restrict__ sidx, const int* __restrict__ scount,
                                 u16* __restrict__ Kg, u16* __restrict__ Vgt) {
  __shared__ u16 tile[64][72];
  __shared__ int rowidx[64];
  const int nspec = scount[64];
  const int j0 = (int)blockIdx.x * 64;
  if (j0 >= nspec) return;
  const int kvh = (int)blockIdx.y;
  const int t = (int)threadIdx.x;
  if (t < 64) rowidx[t] = (j0 + t < nspec) ? sidx[j0 + t] : 0;
  __syncthreads();
  const int r = t >> 2;
  const int s = rowidx[r];
  // K: dest row j (swizzle j&7), source row s (swizzle s&7) -> chunk map cd -> cd^((j^s)&7)
  {
    const int j = j0 + r;
    const u16* srcrow = Kb + (size_t)s * 256 + kvh * 64;
    u16* dstrow = Kg + (size_t)j * 256 + kvh * 64;
    const int x = (j ^ s) & 7;
#pragma unroll
    for (int a = 0; a < 2; ++a) {
      const int cd = (t & 3) * 2 + a;
      *(s16x8*)(dstrow + cd * 8) = *(const s16x8*)(srcrow + ((cd ^ x) * 8));
    }
  }
  // V: gather rows -> LDS -> transposed + chunk-swizzled (d&7)
  {
    const int c = (t & 3) * 16;
    *(s16x8*)&tile[r][c]     = *(const s16x8*)(Vb + (size_t)s * 256 + kvh * 64 + c);
    *(s16x8*)&tile[r][c + 8] = *(const s16x8*)(Vb + (size_t)s * 256 + kvh * 64 + c + 8);
  }
  __syncthreads();
  {
    const int d = t >> 2;
    u16* drow = Vgt + (size_t)(kvh * 64 + d) * 4096 + j0;
#pragma unroll
    for (int a = 0; a < 2; ++a) {
      const int cd = (t & 3) * 2 + a;
      const int cn = cd ^ (d & 7);
      s16x8 o;
#pragma unroll
      for (int e = 0; e < 8; ++e) o[e] = (short)tile[cn * 8 + e][d];
      *(s16x8*)(drow + cd * 8) = o;
    }
  }
}

// ---------------- V transpose: Vb[s][kvh*64+d] -> Vtg[kvh*64+d][s] (swizzled) ----------------
__global__ void vtrans_kernel(const u16* __restrict__ Vb, u16* __restrict__ Vtg) {
  __shared__ u16 tile[64][65];
  const int s0 = (int)blockIdx.x * 64;
  const int kvh = (int)blockIdx.y;
  const int t = (int)threadIdx.x;
  const int r = t >> 2, c4 = (t & 3) * 16;
  *(s16x8*)&tile[r][c4]     = *(const s16x8*)(Vb + (size_t)(s0 + r) * 256 + kvh * 64 + c4);
  *(s16x8*)&tile[r][c4 + 8] = *(const s16x8*)(Vb + (size_t)(s0 + r) * 256 + kvh * 64 + c4 + 8);
  __syncthreads();
  const int d = t >> 2, sc = (t & 3) * 16;
  const int sw = (d & 7) << 3;
#pragma unroll
  for (int a = 0; a < 2; ++a) {
    s16x8 o;
#pragma unroll
    for (int j = 0; j < 8; ++j) o[j] = (short)tile[sc + a * 8 + j][d];
    *(s16x8*)(Vtg + (size_t)(kvh * 64 + d) * 4096 + s0 + ((sc + a * 8) ^ sw)) = o;
  }
}

// ---------------- 128x128 MFMA GEMM core, K=1024 ----------------
// MODE 0: C fp32 out.  MODE 1: QKV with fused RoPE epilogue (K written swizzled).
template <int MODE>
__global__ __launch_bounds__(256, 2)
void gemm128(const u16* __restrict__ A, const u16* __restrict__ BT,
             const float* __restrict__ cosp, const float* __restrict__ sinp,
             u16* __restrict__ Qb, u16* __restrict__ Kb, u16* __restrict__ Vb,
             float* __restrict__ Cf) {
  __shared__ __align__(16) u16 As[128 * 32];
  __shared__ __align__(16) u16 Bs[128 * 32];
  const int t = (int)threadIdx.x;
  const int w = t >> 6;
  const int lane = t & 63;
  const int lr = lane & 15, lg = lane >> 4;
  const int m0 = (int)blockIdx.y * 128;
  const int n0 = (int)blockIdx.x * 128;
  const int wm = (w >> 1) * 64, wn = (w & 1) * 64;

  f32x4 acc[4][4] = {};

  const int srow = t >> 2;        // 0..63
  const int scol = (t & 3) * 8;   // u16 offset within 32-wide k chunk

  for (int k0 = 0; k0 < 1024; k0 += 32) {
#pragma unroll
    for (int i = 0; i < 2; ++i) {
      gload16(A + (size_t)(m0 + i * 64 + srow) * 1024 + k0 + scol, As + i * 2048 + t * 8);
      gload16(BT + (size_t)(n0 + i * 64 + srow) * 1024 + k0 + scol, Bs + i * 2048 + t * 8);
    }
    __syncthreads();
    bf16x8 af[4], bg[4];
#pragma unroll
    for (int mi = 0; mi < 4; ++mi)
      af[mi] = *(const bf16x8*)(As + (wm + mi * 16 + lr) * 32 + lg * 8);
#pragma unroll
    for (int ni = 0; ni < 4; ++ni)
      bg[ni] = *(const bf16x8*)(Bs + (wn + ni * 16 + lr) * 32 + lg * 8);
#pragma unroll
    for (int mi = 0; mi < 4; ++mi)
#pragma unroll
      for (int ni = 0; ni < 4; ++ni)
        acc[mi][ni] = mfma16(af[mi], bg[ni], acc[mi][ni]);
    __syncthreads();
  }

  const int nbase = n0 + wn;  // multiple of 64 (one head per wave N-tile)
#pragma unroll
  for (int mi = 0; mi < 4; ++mi) {
#pragma unroll
    for (int r = 0; r < 4; ++r) {
      const int m = m0 + wm + mi * 16 + lg * 4 + r;
      if (MODE == 0) {
#pragma unroll
        for (int ni = 0; ni < 4; ++ni)
          Cf[(size_t)m * 1024 + nbase + ni * 16 + lr] = acc[mi][ni][r];
      } else {
        if (nbase < 1280) {
          // RoPE for Q or K
          const float* cr = cosp + (size_t)m * 64;
          const float* sr = sinp + (size_t)m * 64;
          float o[4];
#pragma unroll
          for (int ni = 0; ni < 2; ++ni) {
            const int d1 = ni * 16 + lr, d2 = d1 + 32;
            const float x = acc[mi][ni][r], y = acc[mi][ni + 2][r];
            o[ni]     = x * cr[d1] - y * sr[d1];
            o[ni + 2] = y * cr[d2] + x * sr[d2];
          }
          if (nbase < 1024) {
            u16* dst = Qb + (size_t)m * 1024 + nbase;
#pragma unroll
            for (int ni = 0; ni < 4; ++ni) dst[ni * 16 + lr] = f2bf(o[ni]);
          } else {
            u16* dst = Kb + (size_t)m * 256 + (nbase - 1024);
            const int sw = (m & 7) << 3;
#pragma unroll
            for (int ni = 0; ni < 4; ++ni) dst[(ni * 16 + lr) ^ sw] = f2bf(o[ni]);
          }
        } else {
          u16* dst = Vb + (size_t)m * 256 + (nbase - 1280);
#pragma unroll
          for (int ni = 0; ni < 4; ++ni) dst[ni * 16 + lr] = f2bf(acc[mi][ni][r]);
        }
      }
    }
  }
}

// ---------------- flash attention, sentence-sparse ----------------
// local tiles [eos_tile(q0) .. qt] with full mask + packed special-token tiles.
// grid (64 q-tiles, 16 heads), 256 threads = 4 waves x 16 q-rows
__global__ __launch_bounds__(256, 4)
void attn_kernel(const u16* __restrict__ Qb, const u16* __restrict__ Kb,
                 const u16* __restrict__ Vtg, const u16* __restrict__ Kg,
                 const u16* __restrict__ Vgt, const u64* __restrict__ spb,
                 const int* __restrict__ eosi, const int* __restrict__ scount,
                 u16* __restrict__ Ob) {
  __shared__ __align__(16) u16 lds[2][2][4096];  // [buf][K|Vt][64 x 64]

  const int qt = 63 - (int)blockIdx.x;
  const int h = (int)blockIdx.y;
  const int kvh = h >> 2;
  const int t = (int)threadIdx.x;
  const int w = t >> 6;
  const int lane = t & 63;
  const int lr = lane & 15, lg = lane >> 4;
  const int q0 = qt * 64;
  const int q = q0 + w * 16 + lr;       // this lane's q-row
  const int swl = (lr & 7) << 3;        // LDS read swizzle (elems)

  // sparse schedule: gathered special tiles first, then local tiles
  const int tile_lo = eosi[q0] >> 6;        // eos monotone -> min over tile at first row
  const int nsp = scount[tile_lo];          // specials strictly below tile_lo*64
  const int nspt = (nsp + 63) >> 6;
  const int nit = nspt + (qt - tile_lo + 1);

  bf16x8 aq[2];
  {
    const u16* qp = Qb + (size_t)q * 1024 + h * 64 + lg * 8;
    aq[0] = *(const bf16x8*)qp;
    aq[1] = *(const bf16x8*)(qp + 32);
  }
  const int eos_q = eosi[q];

  f32x4 acc[4] = {};      // acc[dt]: d = dt*16 + lg*4 + r, col q = lr
  float mrow = -3.0e38f;
  float lrow = 0.0f;

  const int grow = t >> 3;        // staging row 0..31 (+32i)
  const int gcol = (t & 7) * 8;   // staging col (elems)

  auto STAGE = [&](int buf, int it) {
    const u16 *kp, *vp;
    if (it < nspt) {
      const int kbase = it * 64;
      kp = Kg + (size_t)kbase * 256 + kvh * 64;
      vp = Vgt + (size_t)(kvh * 64) * 4096 + kbase;
    } else {
      const int kbase = (tile_lo + it - nspt) * 64;
      kp = Kb + (size_t)kbase * 256 + kvh * 64;
      vp = Vtg + (size_t)(kvh * 64) * 4096 + kbase;
    }
#pragma unroll
    for (int i = 0; i < 2; ++i) {
      gload16(kp + (size_t)(i * 32 + grow) * 256 + gcol, &lds[buf][0][i * 2048 + t * 8]);
      gload16(vp + (size_t)(i * 32 + grow) * 4096 + gcol, &lds[buf][1][i * 2048 + t * 8]);
    }
  };

  STAGE(0, 0);
  __syncthreads();

  for (int it = 0; it < nit; ++it) {
    if (it + 1 < nit) STAGE((it + 1) & 1, it + 1);
    const u16* Kl = &lds[it & 1][0][0];
    const u16* Vl = &lds[it & 1][1][0];

    // swapped QK^T: st[kt] rows k = kt*16 + lg*4 + r (tile-local), col q = lr
    f32x4 st[4];
#pragma unroll
    for (int kt = 0; kt < 4; ++kt) {
      f32x4 s = {};
#pragma unroll
      for (int c = 0; c < 2; ++c) {
        bf16x8 ak = *(const bf16x8*)(Kl + (kt * 16 + lr) * 64 + ((c * 32 + lg * 8) ^ swl));
        s = mfma16(ak, aq[c], s);
      }
      st[kt] = s;
    }

    // mask
    u64 allowed;
    if (it < nspt) {
      const int rem = nsp - it * 64;  // >= 1
      allowed = (rem >= 64) ? ~0ull : ((1ull << rem) - 1ull);
    } else {
      const int kbase = (tile_lo + it - nspt) * 64;
      const u64 spec = spb[kbase >> 6];
      const int dq = q - kbase;
      const u64 causal = (dq >= 63) ? ~0ull : ((2ull << dq) - 1ull);
      const int de = eos_q - kbase;
      const u64 ge = (de <= 0) ? ~0ull : (de >= 64 ? 0ull : (~0ull << de));
      allowed = causal & (ge | spec);
    }

    // scores -> log2 domain, masked
    float xs[16];
    float tmax = -3.0e38f;
#pragma unroll
    for (int kt = 0; kt < 4; ++kt) {
      const u32 bits = (u32)(allowed >> (kt * 16 + lg * 4)) & 0xFu;
#pragma unroll
      for (int r = 0; r < 4; ++r) {
        const float x = ((bits >> r) & 1u) ? st[kt][r] * 0.18033688011112042f : -3.0e38f;
        xs[kt * 4 + r] = x;
        tmax = fmaxf(tmax, x);
      }
    }
    tmax = fmaxf(tmax, __shfl_xor(tmax, 16));
    tmax = fmaxf(tmax, __shfl_xor(tmax, 32));
    const float mn = fmaxf(mrow, tmax);
    const float resc = exp2f(mrow - mn);
    mrow = mn;

    float rs = 0.0f;
    u32 pk[8];
#pragma unroll
    for (int i = 0; i < 16; i += 2) {
      const float p0 = exp2f(xs[i] - mn);
      const float p1 = exp2f(xs[i + 1] - mn);
      rs += p0 + p1;
      pk[i >> 1] = (u32)f2bf(p0) | ((u32)f2bf(p1) << 16);
    }
    rs += __shfl_xor(rs, 16);
    rs += __shfl_xor(rs, 32);
    lrow = lrow * resc + rs;

#pragma unroll
    for (int dt = 0; dt < 4; ++dt)
#pragma unroll
      for (int r = 0; r < 4; ++r) acc[dt][r] *= resc;

    // PV: B-frag = softmax quad straight from regs
#pragma unroll
    for (int kt = 0; kt < 4; ++kt) {
      union { u32 u[2]; s16x4 v; } cv;
      cv.u[0] = pk[kt * 2]; cv.u[1] = pk[kt * 2 + 1];
      const int vo = (kt * 16 + lg * 4) ^ swl;
#pragma unroll
      for (int dt = 0; dt < 4; ++dt) {
        s16x4 av = *(const s16x4*)(Vl + (dt * 16 + lr) * 64 + vo);
        acc[dt] = mfma16x16(av, cv.v, acc[dt]);
      }
    }
    __syncthreads();
  }

  // epilogue: normalize, store bf16 (S, H*HD)
  const float inv = 1.0f / lrow;
#pragma unroll
  for (int dt = 0; dt < 4; ++dt) {
    const u32 w0 = (u32)f2bf(acc[dt][0] * inv) | ((u32)f2bf(acc[dt][1] * inv) << 16);
    const u32 w1 = (u32)f2bf(acc[dt][2] * inv) | ((u32)f2bf(acc[dt][3] * inv) << 16);
    u32* dst = (u32*)(Ob + (size_t)q * 1024 + h * 64 + dt * 16 + lg * 4);
    dst[0] = w0; dst[1] = w1;
  }
}

// ---------------- launch ----------------
extern "C" void kernel_launch(void* const* d_in, const int* in_sizes, int n_in,
                              void* d_out, int out_size, void* d_ws, size_t ws_size,
                              hipStream_t stream) {
  (void)in_sizes; (void)n_in; (void)out_size; (void)ws_size;
  const float* hidden = (const float*)d_in[0];
  const float* cosp   = (const float*)d_in[1];
  const float* sinp   = (const float*)d_in[2];
  const float* Wq     = (const float*)d_in[3];
  const float* Wk     = (const float*)d_in[4];
  const float* Wv     = (const float*)d_in[5];
  const float* Wo     = (const float*)d_in[6];
  const int* spec     = (const int*)d_in[7];
  const int* eosi     = (const int*)d_in[8];
  float* out = (float*)d_out;

  u16* ws = (u16*)d_ws;
  u16* hbf   = ws;                       // 4096*1024, reused after QKV gemm
  u16* wqkvT = hbf + 4194304;            // 1536*1024 (rows: Wq^T | Wk^T | Wv^T)
  u16* woT   = wqkvT + 1572864;          // 1024*1024
  u16* Qb    = woT + 1048576;            // 4096*1024
  u16* Kb    = Qb + 4194304;             // 4096*256 (chunk-swizzled by row)
  u16* Vb    = Kb + 1048576;             // 4096*256
  u16* Ob    = Vb + 1048576;             // 4096*1024
  // carved out of hbf after the QKV GEMM finishes reading it:
  u16* Vtg   = hbf;                      // 4*64*4096
  u16* Kg    = hbf + 1048576;            // 4096*256 packed special K
  u16* Vgt   = hbf + 2097152;            // 4*64*4096 packed special V^T
  u64* spb   = (u64*)(hbf + 3145728);    // 64 x u64
  int* sidx  = (int*)(hbf + 3146240);    // 4096 int
  int* scnt  = (int*)(hbf + 3154432);    // 65 int

  cast_bf16_kernel<<<dim3(4096), dim3(256), 0, stream>>>(hidden, hbf);
  transpose_cast<<<dim3(32, 32), dim3(32, 8), 0, stream>>>(Wq, wqkvT, 1024, 1024);
  transpose_cast<<<dim3(8, 32), dim3(32, 8), 0, stream>>>(Wk, wqkvT + 1024 * 1024, 1024, 256);
  transpose_cast<<<dim3(8, 32), dim3(32, 8), 0, stream>>>(Wv, wqkvT + 1280 * 1024, 1024, 256);
  transpose_cast<<<dim3(32, 32), dim3(32, 8), 0, stream>>>(Wo, woT, 1024, 1024);

  gemm128<1><<<dim3(12, 32), dim3(256), 0, stream>>>(hbf, wqkvT, cosp, sinp,
                                                     Qb, Kb, Vb, nullptr);
  vtrans_kernel<<<dim3(64, 4), dim3(256), 0, stream>>>(Vb, Vtg);
  specmask_kernel<<<dim3(64), dim3(64), 0, stream>>>(spec, spb);
  spec_gather_kernel<<<dim3(1), dim3(64), 0, stream>>>(spec, sidx, scnt);
  spec_pack_kernel<<<dim3(64, 4), dim3(256), 0, stream>>>(Kb, Vb, sidx, scnt, Kg, Vgt);
  attn_kernel<<<dim3(64, 16), dim3(256), 0, stream>>>(Qb, Kb, Vtg, Kg, Vgt, spb,
                                                      eosi, scnt, Ob);
  gemm128<0><<<dim3(8, 32), dim3(256), 0, stream>>>(Ob, woT, nullptr, nullptr,
                                                    nullptr, nullptr, nullptr, out);
}

// Round 4
// 98.094 us; speedup vs baseline: 3.4543x; 1.2460x over previous
//
#include <hip/hip_runtime.h>

typedef __bf16 bf16x8 __attribute__((ext_vector_type(8)));
typedef float f32x4 __attribute__((ext_vector_type(4)));
typedef short s16x8 __attribute__((ext_vector_type(8)));
typedef short s16x4 __attribute__((ext_vector_type(4)));
typedef unsigned short u16;
typedef unsigned int u32;
typedef unsigned long long u64;

#define S_LEN 4096
#define DMODEL 1024
#define NH 16
#define HD 64

static __device__ __forceinline__ u16 f2bf(float f) {
  union { float f; u32 u; } a; a.f = f;
  u32 r = (a.u + 0x7fffu + ((a.u >> 16) & 1u)) >> 16;
  return (u16)r;
}

static __device__ __forceinline__ f32x4 mfma16(bf16x8 a, bf16x8 b, f32x4 c) {
  return __builtin_amdgcn_mfma_f32_16x16x32_bf16(a, b, c, 0, 0, 0);
}

static __device__ __forceinline__ f32x4 mfma16x16(s16x4 a, s16x4 b, f32x4 c) {
#if __has_builtin(__builtin_amdgcn_mfma_f32_16x16x16bf16_1k)
  return __builtin_amdgcn_mfma_f32_16x16x16bf16_1k(a, b, c, 0, 0, 0);
#else
  asm("v_mfma_f32_16x16x16_bf16 %0, %1, %2, %0" : "+v"(c) : "v"(a), "v"(b));
  return c;
#endif
}

static __device__ __forceinline__ void gload16(const void* g, void* l) {
  __builtin_amdgcn_global_load_lds((const __attribute__((address_space(1))) u32*)g,
                                   (__attribute__((address_space(3))) u32*)l, 16, 0, 0);
}

// ---------------- fused prep: cast + 4 weight transposes + spec scan ----------------
// grid layout (256 thr each):
//   [0,4096)      cast hidden fp32->bf16
//   [4096,5120)   Wq^T   [5120,5376) Wk^T   [5376,5632) Wv^T   [5632,6656) Wo^T
//   6656          spec ballot + prefix + gather + qmeta
__global__ __launch_bounds__(256)
void prep_kernel(const float* __restrict__ hidden, const float* __restrict__ Wq,
                 const float* __restrict__ Wk, const float* __restrict__ Wv,
                 const float* __restrict__ Wo, const int* __restrict__ spec,
                 const int* __restrict__ eosi,
                 u16* __restrict__ hbf, u16* __restrict__ wqkvT, u16* __restrict__ woT,
                 u64* __restrict__ spb, int* __restrict__ sidx, int* __restrict__ scnt,
                 int4* __restrict__ qmeta) {
  __shared__ float ftile[32][33];
  __shared__ u64 smask[64];
  __shared__ int scnt_s[64];
  __shared__ int spref[64];

  const int bx = (int)blockIdx.x;
  const int t = (int)threadIdx.x;

  if (bx < 4096) {  // cast
    const int i = (bx * 256 + t) * 4;
    const float4 v = *(const float4*)(hidden + i);
    uint2 o;
    o.x = (u32)f2bf(v.x) | ((u32)f2bf(v.y) << 16);
    o.y = (u32)f2bf(v.z) | ((u32)f2bf(v.w) << 16);
    *(uint2*)(hbf + i) = o;
    return;
  }
  if (bx < 6656) {  // weight transposes
    const float* W; u16* WT; int N, loc, nbx;
    if (bx < 5120)      { W = Wq; WT = wqkvT;               N = 1024; loc = bx - 4096; nbx = 32; }
    else if (bx < 5376) { W = Wk; WT = wqkvT + 1024 * 1024; N = 256;  loc = bx - 5120; nbx = 8; }
    else if (bx < 5632) { W = Wv; WT = wqkvT + 1280 * 1024; N = 256;  loc = bx - 5376; nbx = 8; }
    else                { W = Wo; WT = woT;                 N = 1024; loc = bx - 5632; nbx = 32; }
    const int n0 = (loc % nbx) * 32, k0 = (loc / nbx) * 32;
    const int tx = t & 31, ty = t >> 5;
#pragma unroll
    for (int i = 0; i < 4; ++i)
      ftile[ty + 8 * i][tx] = W[(size_t)(k0 + ty + 8 * i) * N + n0 + tx];
    __syncthreads();
#pragma unroll
    for (int i = 0; i < 4; ++i)
      WT[(size_t)(n0 + ty + 8 * i) * 1024 + k0 + tx] = f2bf(ftile[tx][ty + 8 * i]);
    return;
  }
  // spec scan block
  const int wv = t >> 6, l = t & 63;
#pragma unroll
  for (int i = 0; i < 16; ++i) {
    const int b = wv * 16 + i;
    const u64 m = __ballot(spec[b * 64 + l] != 0);
    if (l == 0) { smask[b] = m; scnt_s[b] = __popcll(m); }
  }
  __syncthreads();
  if (wv == 0) {
    const int v = scnt_s[l];
    int inc = v;
#pragma unroll
    for (int d = 1; d < 64; d <<= 1) {
      const int o = __shfl_up(inc, d);
      if (l >= d) inc += o;
    }
    spref[l] = inc - v;  // exclusive prefix
    if (l == 63) scnt[0] = inc;
    spb[l] = smask[l];
  }
  __syncthreads();
#pragma unroll
  for (int i = 0; i < 16; ++i) {
    const int b = wv * 16 + i;
    const u64 m = smask[b];
    if ((m >> l) & 1ull)
      sidx[spref[b] + __popcll(m & ((1ull << l) - 1ull))] = b * 64 + l;
  }
  if (t < 64) {
    const int e = eosi[t * 64];
    const int tlo = e >> 6;
    const int nsp = spref[tlo];
    const int nspt = (nsp + 63) >> 6;
    qmeta[t] = make_int4(tlo, nspt, nspt + (t - tlo + 1), nsp);
  }
}

// ---------------- fused pack: V transpose + special K/V^T gather ----------------
// grid (128, 4): bx<64 -> vtrans tile, bx>=64 -> spec pack tile
__global__ __launch_bounds__(256)
void pack_kernel(const u16* __restrict__ Kb, const u16* __restrict__ Vb,
                 const int* __restrict__ sidx, const int* __restrict__ scnt,
                 u16* __restrict__ Vtg, u16* __restrict__ Kg, u16* __restrict__ Vgt) {
  const int kvh = (int)blockIdx.y;
  const int t = (int)threadIdx.x;
  if (blockIdx.x < 64) {
    __shared__ u16 tile[64][65];
    const int s0 = (int)blockIdx.x * 64;
    const int r = t >> 2, c4 = (t & 3) * 16;
    *(s16x8*)&tile[r][c4]     = *(const s16x8*)(Vb + (size_t)(s0 + r) * 256 + kvh * 64 + c4);
    *(s16x8*)&tile[r][c4 + 8] = *(const s16x8*)(Vb + (size_t)(s0 + r) * 256 + kvh * 64 + c4 + 8);
    __syncthreads();
    const int d = t >> 2, sc = (t & 3) * 16;
    const int sw = (d & 7) << 3;
#pragma unroll
    for (int a = 0; a < 2; ++a) {
      s16x8 o;
#pragma unroll
      for (int j = 0; j < 8; ++j) o[j] = (short)tile[sc + a * 8 + j][d];
      *(s16x8*)(Vtg + (size_t)(kvh * 64 + d) * 4096 + s0 + ((sc + a * 8) ^ sw)) = o;
    }
  } else {
    __shared__ u16 tileS[64][72];
    __shared__ int rowidx[64];
    const int nspec = scnt[0];
    const int j0 = ((int)blockIdx.x - 64) * 64;
    if (j0 >= nspec) return;
    if (t < 64) rowidx[t] = (j0 + t < nspec) ? sidx[j0 + t] : 0;
    __syncthreads();
    const int r = t >> 2;
    const int s = rowidx[r];
    {
      const int j = j0 + r;
      const u16* srcrow = Kb + (size_t)s * 256 + kvh * 64;
      u16* dstrow = Kg + (size_t)j * 256 + kvh * 64;
      const int x = (j ^ s) & 7;
#pragma unroll
      for (int a = 0; a < 2; ++a) {
        const int cd = (t & 3) * 2 + a;
        *(s16x8*)(dstrow + cd * 8) = *(const s16x8*)(srcrow + ((cd ^ x) * 8));
      }
    }
    {
      const int c = (t & 3) * 16;
      *(s16x8*)&tileS[r][c]     = *(const s16x8*)(Vb + (size_t)s * 256 + kvh * 64 + c);
      *(s16x8*)&tileS[r][c + 8] = *(const s16x8*)(Vb + (size_t)s * 256 + kvh * 64 + c + 8);
    }
    __syncthreads();
    {
      const int d = t >> 2;
      u16* drow = Vgt + (size_t)(kvh * 64 + d) * 4096 + j0;
#pragma unroll
      for (int a = 0; a < 2; ++a) {
        const int cd = (t & 3) * 2 + a;
        const int cn = cd ^ (d & 7);
        s16x8 o;
#pragma unroll
        for (int e = 0; e < 8; ++e) o[e] = (short)tileS[cn * 8 + e][d];
        *(s16x8*)(drow + cd * 8) = o;
      }
    }
  }
}

// ---------------- 128x128 MFMA GEMM core, K=1024 ----------------
// MODE 0: C fp32 out.  MODE 1: QKV with fused RoPE epilogue (K written swizzled).
template <int MODE>
__global__ __launch_bounds__(256, 2)
void gemm128(const u16* __restrict__ A, const u16* __restrict__ BT,
             const float* __restrict__ cosp, const float* __restrict__ sinp,
             u16* __restrict__ Qb, u16* __restrict__ Kb, u16* __restrict__ Vb,
             float* __restrict__ Cf) {
  __shared__ __align__(16) u16 As[128 * 32];
  __shared__ __align__(16) u16 Bs[128 * 32];
  const int t = (int)threadIdx.x;
  const int w = t >> 6;
  const int lane = t & 63;
  const int lr = lane & 15, lg = lane >> 4;
  const int m0 = (int)blockIdx.y * 128;
  const int n0 = (int)blockIdx.x * 128;
  const int wm = (w >> 1) * 64, wn = (w & 1) * 64;

  f32x4 acc[4][4] = {};

  const int srow = t >> 2;
  const int scol = (t & 3) * 8;

  for (int k0 = 0; k0 < 1024; k0 += 32) {
#pragma unroll
    for (int i = 0; i < 2; ++i) {
      gload16(A + (size_t)(m0 + i * 64 + srow) * 1024 + k0 + scol, As + i * 2048 + t * 8);
      gload16(BT + (size_t)(n0 + i * 64 + srow) * 1024 + k0 + scol, Bs + i * 2048 + t * 8);
    }
    __syncthreads();
    bf16x8 af[4], bg[4];
#pragma unroll
    for (int mi = 0; mi < 4; ++mi)
      af[mi] = *(const bf16x8*)(As + (wm + mi * 16 + lr) * 32 + lg * 8);
#pragma unroll
    for (int ni = 0; ni < 4; ++ni)
      bg[ni] = *(const bf16x8*)(Bs + (wn + ni * 16 + lr) * 32 + lg * 8);
#pragma unroll
    for (int mi = 0; mi < 4; ++mi)
#pragma unroll
      for (int ni = 0; ni < 4; ++ni)
        acc[mi][ni] = mfma16(af[mi], bg[ni], acc[mi][ni]);
    __syncthreads();
  }

  const int nbase = n0 + wn;
#pragma unroll
  for (int mi = 0; mi < 4; ++mi) {
#pragma unroll
    for (int r = 0; r < 4; ++r) {
      const int m = m0 + wm + mi * 16 + lg * 4 + r;
      if (MODE == 0) {
#pragma unroll
        for (int ni = 0; ni < 4; ++ni)
          Cf[(size_t)m * 1024 + nbase + ni * 16 + lr] = acc[mi][ni][r];
      } else {
        if (nbase < 1280) {
          const float* cr = cosp + (size_t)m * 64;
          const float* sr = sinp + (size_t)m * 64;
          float o[4];
#pragma unroll
          for (int ni = 0; ni < 2; ++ni) {
            const int d1 = ni * 16 + lr, d2 = d1 + 32;
            const float x = acc[mi][ni][r], y = acc[mi][ni + 2][r];
            o[ni]     = x * cr[d1] - y * sr[d1];
            o[ni + 2] = y * cr[d2] + x * sr[d2];
          }
          if (nbase < 1024) {
            u16* dst = Qb + (size_t)m * 1024 + nbase;
#pragma unroll
            for (int ni = 0; ni < 4; ++ni) dst[ni * 16 + lr] = f2bf(o[ni]);
          } else {
            u16* dst = Kb + (size_t)m * 256 + (nbase - 1024);
            const int sw = (m & 7) << 3;
#pragma unroll
            for (int ni = 0; ni < 4; ++ni) dst[(ni * 16 + lr) ^ sw] = f2bf(o[ni]);
          }
        } else {
          u16* dst = Vb + (size_t)m * 256 + (nbase - 1280);
#pragma unroll
          for (int ni = 0; ni < 4; ++ni) dst[ni * 16 + lr] = f2bf(acc[mi][ni][r]);
        }
      }
    }
  }
}

// ---------------- flash attention, sentence-sparse, local-first ----------------
// grid (64 q-tiles, 16 heads), 256 threads = 4 waves x 16 q-rows
__global__ __launch_bounds__(256, 4)
void attn_kernel(const u16* __restrict__ Qb, const u16* __restrict__ Kb,
                 const u16* __restrict__ Vtg, const u16* __restrict__ Kg,
                 const u16* __restrict__ Vgt, const u64* __restrict__ spb,
                 const int* __restrict__ eosi, const int4* __restrict__ qmeta,
                 u16* __restrict__ Ob) {
  __shared__ __align__(16) u16 lds[2][2][4096];

  const int qt = 63 - (int)blockIdx.x;
  const int h = (int)blockIdx.y;
  const int kvh = h >> 2;
  const int t = (int)threadIdx.x;
  const int w = t >> 6;
  const int lane = t & 63;
  const int lr = lane & 15, lg = lane >> 4;
  const int q0 = qt * 64;
  const int q = q0 + w * 16 + lr;
  const int swl = (lr & 7) << 3;

  const int4 qm = qmeta[qt];       // {tile_lo, nspt, nit, nsp}
  const int tile_lo = qm.x;
  const int nit = qm.z;
  const int nsp = qm.w;
  const int nloc = qt - tile_lo + 1;

  bf16x8 aq[2];
  {
    const u16* qp = Qb + (size_t)q * 1024 + h * 64 + lg * 8;
    aq[0] = *(const bf16x8*)qp;
    aq[1] = *(const bf16x8*)(qp + 32);
  }
  const int eos_q = eosi[q];

  f32x4 acc[4] = {};
  float mrow = -3.0e38f;
  float lrow = 0.0f;

  const int grow = t >> 3;
  const int gcol = (t & 7) * 8;

  auto STAGE = [&](int buf, int it) {
    const u16 *kp, *vp;
    if (it < nloc) {
      const int kbase = (tile_lo + it) * 64;
      kp = Kb + (size_t)kbase * 256 + kvh * 64;
      vp = Vtg + (size_t)(kvh * 64) * 4096 + kbase;
    } else {
      const int jb = (it - nloc) * 64;
      kp = Kg + (size_t)jb * 256 + kvh * 64;
      vp = Vgt + (size_t)(kvh * 64) * 4096 + jb;
    }
#pragma unroll
    for (int i = 0; i < 2; ++i) {
      gload16(kp + (size_t)(i * 32 + grow) * 256 + gcol, &lds[buf][0][i * 2048 + t * 8]);
      gload16(vp + (size_t)(i * 32 + grow) * 4096 + gcol, &lds[buf][1][i * 2048 + t * 8]);
    }
  };

  STAGE(0, 0);
  __syncthreads();

  for (int it = 0; it < nit; ++it) {
    if (it + 1 < nit) STAGE((it + 1) & 1, it + 1);
    const u16* Kl = &lds[it & 1][0][0];
    const u16* Vl = &lds[it & 1][1][0];

    f32x4 st[4];
#pragma unroll
    for (int kt = 0; kt < 4; ++kt) {
      f32x4 s = {};
#pragma unroll
      for (int c = 0; c < 2; ++c) {
        bf16x8 ak = *(const bf16x8*)(Kl + (kt * 16 + lr) * 64 + ((c * 32 + lg * 8) ^ swl));
        s = mfma16(ak, aq[c], s);
      }
      st[kt] = s;
    }

    u64 allowed;
    if (it < nloc) {
      const int kbase = (tile_lo + it) * 64;
      const u64 spec = spb[tile_lo + it];
      const int dq = q - kbase;
      const u64 causal = (dq >= 63) ? ~0ull : ((2ull << dq) - 1ull);
      const int de = eos_q - kbase;
      const u64 ge = (de <= 0) ? ~0ull : (de >= 64 ? 0ull : (~0ull << de));
      allowed = causal & (ge | spec);
    } else {
      const int rem = nsp - (it - nloc) * 64;
      allowed = (rem >= 64) ? ~0ull : ((1ull << rem) - 1ull);
    }

    float xs[16];
    float tmax = -3.0e38f;
#pragma unroll
    for (int kt = 0; kt < 4; ++kt) {
      const u32 bits = (u32)(allowed >> (kt * 16 + lg * 4)) & 0xFu;
#pragma unroll
      for (int r = 0; r < 4; ++r) {
        const float x = ((bits >> r) & 1u) ? st[kt][r] * 0.18033688011112042f : -3.0e38f;
        xs[kt * 4 + r] = x;
        tmax = fmaxf(tmax, x);
      }
    }
    tmax = fmaxf(tmax, __shfl_xor(tmax, 16));
    tmax = fmaxf(tmax, __shfl_xor(tmax, 32));
    const float mn = fmaxf(mrow, tmax);
    const float resc = exp2f(mrow - mn);
    mrow = mn;

    float rs = 0.0f;
    u32 pk[8];
#pragma unroll
    for (int i = 0; i < 16; i += 2) {
      const float p0 = exp2f(xs[i] - mn);
      const float p1 = exp2f(xs[i + 1] - mn);
      rs += p0 + p1;
      pk[i >> 1] = (u32)f2bf(p0) | ((u32)f2bf(p1) << 16);
    }
    rs += __shfl_xor(rs, 16);
    rs += __shfl_xor(rs, 32);
    lrow = lrow * resc + rs;

#pragma unroll
    for (int dt = 0; dt < 4; ++dt)
#pragma unroll
      for (int r = 0; r < 4; ++r) acc[dt][r] *= resc;

#pragma unroll
    for (int kt = 0; kt < 4; ++kt) {
      union { u32 u[2]; s16x4 v; } cv;
      cv.u[0] = pk[kt * 2]; cv.u[1] = pk[kt * 2 + 1];
      const int vo = (kt * 16 + lg * 4) ^ swl;
#pragma unroll
      for (int dt = 0; dt < 4; ++dt) {
        s16x4 av = *(const s16x4*)(Vl + (dt * 16 + lr) * 64 + vo);
        acc[dt] = mfma16x16(av, cv.v, acc[dt]);
      }
    }
    __syncthreads();
  }

  const float inv = 1.0f / lrow;
#pragma unroll
  for (int dt = 0; dt < 4; ++dt) {
    const u32 w0 = (u32)f2bf(acc[dt][0] * inv) | ((u32)f2bf(acc[dt][1] * inv) << 16);
    const u32 w1 = (u32)f2bf(acc[dt][2] * inv) | ((u32)f2bf(acc[dt][3] * inv) << 16);
    u32* dst = (u32*)(Ob + (size_t)q * 1024 + h * 64 + dt * 16 + lg * 4);
    dst[0] = w0; dst[1] = w1;
  }
}

// ---------------- launch ----------------
extern "C" void kernel_launch(void* const* d_in, const int* in_sizes, int n_in,
                              void* d_out, int out_size, void* d_ws, size_t ws_size,
                              hipStream_t stream) {
  (void)in_sizes; (void)n_in; (void)out_size; (void)ws_size;
  const float* hidden = (const float*)d_in[0];
  const float* cosp   = (const float*)d_in[1];
  const float* sinp   = (const float*)d_in[2];
  const float* Wq     = (const float*)d_in[3];
  const float* Wk     = (const float*)d_in[4];
  const float* Wv     = (const float*)d_in[5];
  const float* Wo     = (const float*)d_in[6];
  const int* spec     = (const int*)d_in[7];
  const int* eosi     = (const int*)d_in[8];
  float* out = (float*)d_out;

  u16* ws = (u16*)d_ws;
  u16* hbf   = ws;                       // 4096*1024, reused after QKV gemm
  u16* wqkvT = hbf + 4194304;            // 1536*1024
  u16* woT   = wqkvT + 1572864;          // 1024*1024
  u16* Qb    = woT + 1048576;            // 4096*1024
  u16* Kb    = Qb + 4194304;             // 4096*256 (chunk-swizzled by row)
  u16* Vb    = Kb + 1048576;             // 4096*256
  u16* Ob    = Vb + 1048576;             // 4096*1024
  u16* tail  = Ob + 4194304;             // spec metadata (outside hbf: prep writes both)
  u64* spb   = (u64*)tail;               // 64 x u64
  int* sidx  = (int*)(tail + 256);       // 4096 int
  int* scnt  = (int*)(tail + 8448);      // 1 int
  int4* qmeta = (int4*)(tail + 8512);    // 64 x int4
  // carved out of hbf after the QKV GEMM finishes reading it:
  u16* Vtg   = hbf;                      // 4*64*4096
  u16* Kg    = hbf + 1048576;            // 4096*256 packed special K
  u16* Vgt   = hbf + 2097152;            // 4*64*4096 packed special V^T

  prep_kernel<<<dim3(6657), dim3(256), 0, stream>>>(hidden, Wq, Wk, Wv, Wo, spec, eosi,
                                                    hbf, wqkvT, woT, spb, sidx, scnt, qmeta);
  gemm128<1><<<dim3(12, 32), dim3(256), 0, stream>>>(hbf, wqkvT, cosp, sinp,
                                                     Qb, Kb, Vb, nullptr);
  pack_kernel<<<dim3(128, 4), dim3(256), 0, stream>>>(Kb, Vb, sidx, scnt, Vtg, Kg, Vgt);
  attn_kernel<<<dim3(64, 16), dim3(256), 0, stream>>>(Qb, Kb, Vtg, Kg, Vgt, spb,
                                                      eosi, qmeta, Ob);
  gemm128<0><<<dim3(8, 32), dim3(256), 0, stream>>>(Ob, woT, nullptr, nullptr,
                                                    nullptr, nullptr, nullptr, out);
}

// Round 5
// 93.387 us; speedup vs baseline: 3.6284x; 1.0504x over previous
//
#include <hip/hip_runtime.h>

typedef __bf16 bf16x8 __attribute__((ext_vector_type(8)));
typedef float f32x4 __attribute__((ext_vector_type(4)));
typedef short s16x8 __attribute__((ext_vector_type(8)));
typedef short s16x4 __attribute__((ext_vector_type(4)));
typedef unsigned short u16;
typedef unsigned int u32;
typedef unsigned long long u64;

#define S_LEN 4096
#define DMODEL 1024
#define NH 16
#define HD 64

static __device__ __forceinline__ u16 f2bf(float f) {
  union { float f; u32 u; } a; a.f = f;
  u32 r = (a.u + 0x7fffu + ((a.u >> 16) & 1u)) >> 16;
  return (u16)r;
}

static __device__ __forceinline__ f32x4 mfma16(bf16x8 a, bf16x8 b, f32x4 c) {
  return __builtin_amdgcn_mfma_f32_16x16x32_bf16(a, b, c, 0, 0, 0);
}

static __device__ __forceinline__ f32x4 mfma16x16(s16x4 a, s16x4 b, f32x4 c) {
#if __has_builtin(__builtin_amdgcn_mfma_f32_16x16x16bf16_1k)
  return __builtin_amdgcn_mfma_f32_16x16x16bf16_1k(a, b, c, 0, 0, 0);
#else
  asm("v_mfma_f32_16x16x16_bf16 %0, %1, %2, %0" : "+v"(c) : "v"(a), "v"(b));
  return c;
#endif
}

static __device__ __forceinline__ void gload16(const void* g, void* l) {
  __builtin_amdgcn_global_load_lds((const __attribute__((address_space(1))) u32*)g,
                                   (__attribute__((address_space(3))) u32*)l, 16, 0, 0);
}

// ---------------- fused prep: cast + 4 weight transposes + spec scan ----------------
__global__ __launch_bounds__(256)
void prep_kernel(const float* __restrict__ hidden, const float* __restrict__ Wq,
                 const float* __restrict__ Wk, const float* __restrict__ Wv,
                 const float* __restrict__ Wo, const int* __restrict__ spec,
                 const int* __restrict__ eosi,
                 u16* __restrict__ hbf, u16* __restrict__ wqkvT, u16* __restrict__ woT,
                 u64* __restrict__ spb, int* __restrict__ sidx, int* __restrict__ scnt,
                 int4* __restrict__ qmeta) {
  __shared__ float ftile[32][33];
  __shared__ u64 smask[64];
  __shared__ int scnt_s[64];
  __shared__ int spref[64];

  const int bx = (int)blockIdx.x;
  const int t = (int)threadIdx.x;

  if (bx < 4096) {  // cast
    const int i = (bx * 256 + t) * 4;
    const float4 v = *(const float4*)(hidden + i);
    uint2 o;
    o.x = (u32)f2bf(v.x) | ((u32)f2bf(v.y) << 16);
    o.y = (u32)f2bf(v.z) | ((u32)f2bf(v.w) << 16);
    *(uint2*)(hbf + i) = o;
    return;
  }
  if (bx < 6656) {  // weight transposes
    const float* W; u16* WT; int N, loc, nbx;
    if (bx < 5120)      { W = Wq; WT = wqkvT;               N = 1024; loc = bx - 4096; nbx = 32; }
    else if (bx < 5376) { W = Wk; WT = wqkvT + 1024 * 1024; N = 256;  loc = bx - 5120; nbx = 8; }
    else if (bx < 5632) { W = Wv; WT = wqkvT + 1280 * 1024; N = 256;  loc = bx - 5376; nbx = 8; }
    else                { W = Wo; WT = woT;                 N = 1024; loc = bx - 5632; nbx = 32; }
    const int n0 = (loc % nbx) * 32, k0 = (loc / nbx) * 32;
    const int tx = t & 31, ty = t >> 5;
#pragma unroll
    for (int i = 0; i < 4; ++i)
      ftile[ty + 8 * i][tx] = W[(size_t)(k0 + ty + 8 * i) * N + n0 + tx];
    __syncthreads();
#pragma unroll
    for (int i = 0; i < 4; ++i)
      WT[(size_t)(n0 + ty + 8 * i) * 1024 + k0 + tx] = f2bf(ftile[tx][ty + 8 * i]);
    return;
  }
  // spec scan block
  const int wv = t >> 6, l = t & 63;
#pragma unroll
  for (int i = 0; i < 16; ++i) {
    const int b = wv * 16 + i;
    const u64 m = __ballot(spec[b * 64 + l] != 0);
    if (l == 0) { smask[b] = m; scnt_s[b] = __popcll(m); }
  }
  __syncthreads();
  if (wv == 0) {
    const int v = scnt_s[l];
    int inc = v;
#pragma unroll
    for (int d = 1; d < 64; d <<= 1) {
      const int o = __shfl_up(inc, d);
      if (l >= d) inc += o;
    }
    spref[l] = inc - v;  // exclusive prefix
    if (l == 63) scnt[0] = inc;
    spb[l] = smask[l];
  }
  __syncthreads();
#pragma unroll
  for (int i = 0; i < 16; ++i) {
    const int b = wv * 16 + i;
    const u64 m = smask[b];
    if ((m >> l) & 1ull)
      sidx[spref[b] + __popcll(m & ((1ull << l) - 1ull))] = b * 64 + l;
  }
  if (t < 64) {
    const int e = eosi[t * 64];
    const int tlo = e >> 6;
    const int nsp = spref[tlo];
    const int nspt = (nsp + 63) >> 6;
    qmeta[t] = make_int4(tlo, nspt, nspt + (t - tlo + 1), nsp);
  }
}

// ---------------- pack: special K rows + special V^T cols (from Vtg) ----------------
// grid (64, 4), early-exit past nspec tiles
__global__ __launch_bounds__(256)
void pack_kernel(const u16* __restrict__ Kb, const u16* __restrict__ Vtg,
                 const int* __restrict__ sidx, const int* __restrict__ scnt,
                 u16* __restrict__ Kg, u16* __restrict__ Vgt) {
  __shared__ int rowidx[64];
  const int nspec = scnt[0];
  const int j0 = (int)blockIdx.x * 64;
  if (j0 >= nspec) return;
  const int kvh = (int)blockIdx.y;
  const int t = (int)threadIdx.x;
  if (t < 64) rowidx[t] = (j0 + t < nspec) ? sidx[j0 + t] : 0;
  __syncthreads();
  // K gather: dest row j (swz j&7) <- src row s (swz s&7): chunk cd <- cd^((j^s)&7)
  {
    const int r = t >> 2;
    const int s = rowidx[r];
    const int j = j0 + r;
    const u16* srcrow = Kb + (size_t)s * 256 + kvh * 64;
    u16* dstrow = Kg + (size_t)j * 256 + kvh * 64;
    const int x = (j ^ s) & 7;
#pragma unroll
    for (int a = 0; a < 2; ++a) {
      const int cd = (t & 3) * 2 + a;
      *(s16x8*)(dstrow + cd * 8) = *(const s16x8*)(srcrow + ((cd ^ x) * 8));
    }
  }
  // V gather: Vgt[d][j0+jl] <- Vtg[d][sidx[j0+jl]] (both sides chunk-swizzled by d&7)
  {
    const int d = t >> 2;
    const u16* srcrow = Vtg + (size_t)(kvh * 64 + d) * 4096;
    u16* drow = Vgt + (size_t)(kvh * 64 + d) * 4096 + j0;
    const int xd = (d & 7) << 3;
#pragma unroll
    for (int a = 0; a < 2; ++a) {
      const int jc = (t & 3) * 2 + a;  // chunk of 8 within 64
      s16x8 o;
#pragma unroll
      for (int e = 0; e < 8; ++e) {
        const int s = rowidx[jc * 8 + e];
        o[e] = (short)srcrow[(s & ~63) + ((s & 63) ^ xd)];
      }
      *(s16x8*)(drow + ((jc * 8) ^ xd)) = o;
    }
  }
}

// ---------------- 128x64 MFMA GEMM core, K=1024, 4 waves of 32x64 ----------------
// MODE 0: C fp32 out.  MODE 1: QKV, RoPE fused; K swizzled; V written transposed to Vtg.
template <int MODE>
__global__ __launch_bounds__(256, 3)
void gemm128(const u16* __restrict__ A, const u16* __restrict__ BT,
             const float* __restrict__ cosp, const float* __restrict__ sinp,
             u16* __restrict__ Qb, u16* __restrict__ Kb, u16* __restrict__ Vtg,
             float* __restrict__ Cf) {
  __shared__ __align__(16) u16 As[128 * 32];
  __shared__ __align__(16) u16 Bs[64 * 32];
  const int t = (int)threadIdx.x;
  const int w = t >> 6;
  const int lane = t & 63;
  const int lr = lane & 15, lg = lane >> 4;
  const int m0 = (int)blockIdx.y * 128;
  const int n0 = (int)blockIdx.x * 64;   // one head (or head-half-pair) per block
  const int wm = w * 32;

  f32x4 acc[2][4] = {};

  const int srow = t >> 2;        // 0..63
  const int scol = (t & 3) * 8;   // u16 offset within 32-wide k chunk

  for (int k0 = 0; k0 < 1024; k0 += 32) {
    gload16(A + (size_t)(m0 + srow) * 1024 + k0 + scol, As + t * 8);
    gload16(A + (size_t)(m0 + 64 + srow) * 1024 + k0 + scol, As + 2048 + t * 8);
    gload16(BT + (size_t)(n0 + srow) * 1024 + k0 + scol, Bs + t * 8);
    __syncthreads();
    bf16x8 af[2], bg[4];
#pragma unroll
    for (int mi = 0; mi < 2; ++mi)
      af[mi] = *(const bf16x8*)(As + (wm + mi * 16 + lr) * 32 + lg * 8);
#pragma unroll
    for (int ni = 0; ni < 4; ++ni)
      bg[ni] = *(const bf16x8*)(Bs + (ni * 16 + lr) * 32 + lg * 8);
#pragma unroll
    for (int mi = 0; mi < 2; ++mi)
#pragma unroll
      for (int ni = 0; ni < 4; ++ni)
        acc[mi][ni] = mfma16(af[mi], bg[ni], acc[mi][ni]);
    __syncthreads();
  }

  if (MODE == 0) {
#pragma unroll
    for (int mi = 0; mi < 2; ++mi)
#pragma unroll
      for (int r = 0; r < 4; ++r) {
        const int m = m0 + wm + mi * 16 + lg * 4 + r;
#pragma unroll
        for (int ni = 0; ni < 4; ++ni)
          Cf[(size_t)m * 1024 + n0 + ni * 16 + lr] = acc[mi][ni][r];
      }
  } else if (n0 < 1280) {
    // RoPE (Q or K): pair (d, d+32) = (acc[mi][ni], acc[mi][ni+2])
#pragma unroll
    for (int mi = 0; mi < 2; ++mi)
#pragma unroll
      for (int r = 0; r < 4; ++r) {
        const int m = m0 + wm + mi * 16 + lg * 4 + r;
        const float* cr = cosp + (size_t)m * 64;
        const float* sr = sinp + (size_t)m * 64;
        float o[4];
#pragma unroll
        for (int ni = 0; ni < 2; ++ni) {
          const int d1 = ni * 16 + lr, d2 = d1 + 32;
          const float x = acc[mi][ni][r], y = acc[mi][ni + 2][r];
          o[ni]     = x * cr[d1] - y * sr[d1];
          o[ni + 2] = y * cr[d2] + x * sr[d2];
        }
        if (n0 < 1024) {
          u16* dst = Qb + (size_t)m * 1024 + n0;
#pragma unroll
          for (int ni = 0; ni < 4; ++ni) dst[ni * 16 + lr] = f2bf(o[ni]);
        } else {
          u16* dst = Kb + (size_t)m * 256 + (n0 - 1024);
          const int sw = (m & 7) << 3;
#pragma unroll
          for (int ni = 0; ni < 4; ++ni) dst[(ni * 16 + lr) ^ sw] = f2bf(o[ni]);
        }
      }
  } else {
    // V: write transposed + chunk-swizzled directly into Vtg[kvh*64+d][s]
    const int kvh = (n0 - 1280) >> 6;
#pragma unroll
    for (int ni = 0; ni < 4; ++ni) {
      const int d = ni * 16 + lr;
      u16* vrow = Vtg + (size_t)(kvh * 64 + d) * 4096;
      const int xd = (d & 7) << 3;
#pragma unroll
      for (int mi = 0; mi < 2; ++mi) {
        const int sb = m0 + wm + mi * 16 + lg * 4;
        const int os = (sb & ~63) | ((sb & 63) ^ xd);
        uint2 pkv;
        pkv.x = (u32)f2bf(acc[mi][ni][0]) | ((u32)f2bf(acc[mi][ni][1]) << 16);
        pkv.y = (u32)f2bf(acc[mi][ni][2]) | ((u32)f2bf(acc[mi][ni][3]) << 16);
        *(uint2*)(vrow + os) = pkv;
      }
    }
  }
}

// ---------------- flash attention, sentence-sparse, local-first ----------------
// grid (64 q-tiles, 16 heads), 256 threads = 4 waves x 16 q-rows
__global__ __launch_bounds__(256, 4)
void attn_kernel(const u16* __restrict__ Qb, const u16* __restrict__ Kb,
                 const u16* __restrict__ Vtg, const u16* __restrict__ Kg,
                 const u16* __restrict__ Vgt, const u64* __restrict__ spb,
                 const int* __restrict__ eosi, const int4* __restrict__ qmeta,
                 u16* __restrict__ Ob) {
  __shared__ __align__(16) u16 lds[2][2][4096];

  const int qt = 63 - (int)blockIdx.x;
  const int h = (int)blockIdx.y;
  const int kvh = h >> 2;
  const int t = (int)threadIdx.x;
  const int w = t >> 6;
  const int lane = t & 63;
  const int lr = lane & 15, lg = lane >> 4;
  const int q0 = qt * 64;
  const int q = q0 + w * 16 + lr;
  const int swl = (lr & 7) << 3;

  const int4 qm = qmeta[qt];       // {tile_lo, nspt, nit, nsp}
  const int tile_lo = qm.x;
  const int nit = qm.z;
  const int nsp = qm.w;
  const int nloc = qt - tile_lo + 1;

  bf16x8 aq[2];
  {
    const u16* qp = Qb + (size_t)q * 1024 + h * 64 + lg * 8;
    aq[0] = *(const bf16x8*)qp;
    aq[1] = *(const bf16x8*)(qp + 32);
  }
  const int eos_q = eosi[q];

  f32x4 acc[4] = {};
  float mrow = -3.0e38f;
  float lrow = 0.0f;

  const int grow = t >> 3;
  const int gcol = (t & 7) * 8;

  auto STAGE = [&](int buf, int it) {
    const u16 *kp, *vp;
    if (it < nloc) {
      const int kbase = (tile_lo + it) * 64;
      kp = Kb + (size_t)kbase * 256 + kvh * 64;
      vp = Vtg + (size_t)(kvh * 64) * 4096 + kbase;
    } else {
      const int jb = (it - nloc) * 64;
      kp = Kg + (size_t)jb * 256 + kvh * 64;
      vp = Vgt + (size_t)(kvh * 64) * 4096 + jb;
    }
#pragma unroll
    for (int i = 0; i < 2; ++i) {
      gload16(kp + (size_t)(i * 32 + grow) * 256 + gcol, &lds[buf][0][i * 2048 + t * 8]);
      gload16(vp + (size_t)(i * 32 + grow) * 4096 + gcol, &lds[buf][1][i * 2048 + t * 8]);
    }
  };

  STAGE(0, 0);
  __syncthreads();

  for (int it = 0; it < nit; ++it) {
    if (it + 1 < nit) STAGE((it + 1) & 1, it + 1);
    const u16* Kl = &lds[it & 1][0][0];
    const u16* Vl = &lds[it & 1][1][0];

    f32x4 st[4];
#pragma unroll
    for (int kt = 0; kt < 4; ++kt) {
      f32x4 s = {};
#pragma unroll
      for (int c = 0; c < 2; ++c) {
        bf16x8 ak = *(const bf16x8*)(Kl + (kt * 16 + lr) * 64 + ((c * 32 + lg * 8) ^ swl));
        s = mfma16(ak, aq[c], s);
      }
      st[kt] = s;
    }

    u64 allowed;
    if (it < nloc) {
      const int kbase = (tile_lo + it) * 64;
      const u64 spec = spb[tile_lo + it];
      const int dq = q - kbase;
      const u64 causal = (dq >= 63) ? ~0ull : ((2ull << dq) - 1ull);
      const int de = eos_q - kbase;
      const u64 ge = (de <= 0) ? ~0ull : (de >= 64 ? 0ull : (~0ull << de));
      allowed = causal & (ge | spec);
    } else {
      const int rem = nsp - (it - nloc) * 64;
      allowed = (rem >= 64) ? ~0ull : ((1ull << rem) - 1ull);
    }

    float xs[16];
    float tmax = -3.0e38f;
#pragma unroll
    for (int kt = 0; kt < 4; ++kt) {
      const u32 bits = (u32)(allowed >> (kt * 16 + lg * 4)) & 0xFu;
#pragma unroll
      for (int r = 0; r < 4; ++r) {
        const float x = ((bits >> r) & 1u) ? st[kt][r] * 0.18033688011112042f : -3.0e38f;
        xs[kt * 4 + r] = x;
        tmax = fmaxf(tmax, x);
      }
    }
    tmax = fmaxf(tmax, __shfl_xor(tmax, 16));
    tmax = fmaxf(tmax, __shfl_xor(tmax, 32));
    const float mn = fmaxf(mrow, tmax);
    const float resc = exp2f(mrow - mn);
    mrow = mn;

    float rs = 0.0f;
    u32 pk[8];
#pragma unroll
    for (int i = 0; i < 16; i += 2) {
      const float p0 = exp2f(xs[i] - mn);
      const float p1 = exp2f(xs[i + 1] - mn);
      rs += p0 + p1;
      pk[i >> 1] = (u32)f2bf(p0) | ((u32)f2bf(p1) << 16);
    }
    rs += __shfl_xor(rs, 16);
    rs += __shfl_xor(rs, 32);
    lrow = lrow * resc + rs;

#pragma unroll
    for (int dt = 0; dt < 4; ++dt)
#pragma unroll
      for (int r = 0; r < 4; ++r) acc[dt][r] *= resc;

#pragma unroll
    for (int kt = 0; kt < 4; ++kt) {
      union { u32 u[2]; s16x4 v; } cv;
      cv.u[0] = pk[kt * 2]; cv.u[1] = pk[kt * 2 + 1];
      const int vo = (kt * 16 + lg * 4) ^ swl;
#pragma unroll
      for (int dt = 0; dt < 4; ++dt) {
        s16x4 av = *(const s16x4*)(Vl + (dt * 16 + lr) * 64 + vo);
        acc[dt] = mfma16x16(av, cv.v, acc[dt]);
      }
    }
    __syncthreads();
  }

  const float inv = 1.0f / lrow;
#pragma unroll
  for (int dt = 0; dt < 4; ++dt) {
    const u32 w0 = (u32)f2bf(acc[dt][0] * inv) | ((u32)f2bf(acc[dt][1] * inv) << 16);
    const u32 w1 = (u32)f2bf(acc[dt][2] * inv) | ((u32)f2bf(acc[dt][3] * inv) << 16);
    u32* dst = (u32*)(Ob + (size_t)q * 1024 + h * 64 + dt * 16 + lg * 4);
    dst[0] = w0; dst[1] = w1;
  }
}

// ---------------- launch ----------------
extern "C" void kernel_launch(void* const* d_in, const int* in_sizes, int n_in,
                              void* d_out, int out_size, void* d_ws, size_t ws_size,
                              hipStream_t stream) {
  (void)in_sizes; (void)n_in; (void)out_size; (void)ws_size;
  const float* hidden = (const float*)d_in[0];
  const float* cosp   = (const float*)d_in[1];
  const float* sinp   = (const float*)d_in[2];
  const float* Wq     = (const float*)d_in[3];
  const float* Wk     = (const float*)d_in[4];
  const float* Wv     = (const float*)d_in[5];
  const float* Wo     = (const float*)d_in[6];
  const int* spec     = (const int*)d_in[7];
  const int* eosi     = (const int*)d_in[8];
  float* out = (float*)d_out;

  u16* ws = (u16*)d_ws;
  u16* hbf   = ws;                       // 4096*1024, reused after QKV gemm
  u16* wqkvT = hbf + 4194304;            // 1536*1024
  u16* woT   = wqkvT + 1572864;          // 1024*1024
  u16* Qb    = woT + 1048576;            // 4096*1024
  u16* Kb    = Qb + 4194304;             // 4096*256 (chunk-swizzled by row)
  u16* Vtg   = Kb + 1048576;             // 4*64*4096 transposed V (written by gemm<1>)
  u16* Ob    = Vtg + 1048576;            // 4096*1024
  u16* tail  = Ob + 4194304;             // spec metadata
  u64* spb   = (u64*)tail;               // 64 x u64
  int* sidx  = (int*)(tail + 256);       // 4096 int
  int* scnt  = (int*)(tail + 8448);      // 1 int
  int4* qmeta = (int4*)(tail + 8512);    // 64 x int4
  // aliased onto hbf after gemm<1> has consumed it:
  u16* Kg    = hbf;                      // 4096*256 packed special K
  u16* Vgt   = hbf + 1048576;            // 4*64*4096 packed special V^T

  prep_kernel<<<dim3(6657), dim3(256), 0, stream>>>(hidden, Wq, Wk, Wv, Wo, spec, eosi,
                                                    hbf, wqkvT, woT, spb, sidx, scnt, qmeta);
  gemm128<1><<<dim3(24, 32), dim3(256), 0, stream>>>(hbf, wqkvT, cosp, sinp,
                                                     Qb, Kb, Vtg, nullptr);
  pack_kernel<<<dim3(64, 4), dim3(256), 0, stream>>>(Kb, Vtg, sidx, scnt, Kg, Vgt);
  attn_kernel<<<dim3(64, 16), dim3(256), 0, stream>>>(Qb, Kb, Vtg, Kg, Vgt, spb,
                                                      eosi, qmeta, Ob);
  gemm128<0><<<dim3(16, 32), dim3(256), 0, stream>>>(Ob, woT, nullptr, nullptr,
                                                     nullptr, nullptr, nullptr, out);
}

// Round 6
// 90.071 us; speedup vs baseline: 3.7620x; 1.0368x over previous
//
#include <hip/hip_runtime.h>

typedef __bf16 bf16x8 __attribute__((ext_vector_type(8)));
typedef float f32x4 __attribute__((ext_vector_type(4)));
typedef short s16x8 __attribute__((ext_vector_type(8)));
typedef short s16x4 __attribute__((ext_vector_type(4)));
typedef unsigned short u16;
typedef unsigned int u32;
typedef unsigned long long u64;

#define S_LEN 4096
#define DMODEL 1024
#define NH 16
#define HD 64

static __device__ __forceinline__ u16 f2bf(float f) {
  union { float f; u32 u; } a; a.f = f;
  u32 r = (a.u + 0x7fffu + ((a.u >> 16) & 1u)) >> 16;
  return (u16)r;
}

static __device__ __forceinline__ f32x4 mfma16(bf16x8 a, bf16x8 b, f32x4 c) {
  return __builtin_amdgcn_mfma_f32_16x16x32_bf16(a, b, c, 0, 0, 0);
}

static __device__ __forceinline__ f32x4 mfma16x16(s16x4 a, s16x4 b, f32x4 c) {
#if __has_builtin(__builtin_amdgcn_mfma_f32_16x16x16bf16_1k)
  return __builtin_amdgcn_mfma_f32_16x16x16bf16_1k(a, b, c, 0, 0, 0);
#else
  asm("v_mfma_f32_16x16x16_bf16 %0, %1, %2, %0" : "+v"(c) : "v"(a), "v"(b));
  return c;
#endif
}

static __device__ __forceinline__ void gload16(const void* g, void* l) {
  __builtin_amdgcn_global_load_lds((const __attribute__((address_space(1))) u32*)g,
                                   (__attribute__((address_space(3))) u32*)l, 16, 0, 0);
}

// bijective chunked XCD swizzle (requires nwg % 8 == 0): consecutive virtual
// ids land on the SAME XCD -> operand-panel reuse hits that XCD's L2.
static __device__ __forceinline__ int xcd_swz(int id, int nwg) {
  return (id & 7) * (nwg >> 3) + (id >> 3);
}

// ---------------- fused prep: cast + 4 weight transposes + spec scan ----------------
__global__ __launch_bounds__(256)
void prep_kernel(const float* __restrict__ hidden, const float* __restrict__ Wq,
                 const float* __restrict__ Wk, const float* __restrict__ Wv,
                 const float* __restrict__ Wo, const int* __restrict__ spec,
                 const int* __restrict__ eosi,
                 u16* __restrict__ hbf, u16* __restrict__ wqkvT, u16* __restrict__ woT,
                 u64* __restrict__ spb, int* __restrict__ sidx, int* __restrict__ scnt,
                 int4* __restrict__ qmeta) {
  __shared__ float ftile[32][33];
  __shared__ u64 smask[64];
  __shared__ int scnt_s[64];
  __shared__ int spref[64];

  const int bx = (int)blockIdx.x;
  const int t = (int)threadIdx.x;

  if (bx < 4096) {  // cast
    const int i = (bx * 256 + t) * 4;
    const float4 v = *(const float4*)(hidden + i);
    uint2 o;
    o.x = (u32)f2bf(v.x) | ((u32)f2bf(v.y) << 16);
    o.y = (u32)f2bf(v.z) | ((u32)f2bf(v.w) << 16);
    *(uint2*)(hbf + i) = o;
    return;
  }
  if (bx < 6656) {  // weight transposes
    const float* W; u16* WT; int N, loc, nbx;
    if (bx < 5120)      { W = Wq; WT = wqkvT;               N = 1024; loc = bx - 4096; nbx = 32; }
    else if (bx < 5376) { W = Wk; WT = wqkvT + 1024 * 1024; N = 256;  loc = bx - 5120; nbx = 8; }
    else if (bx < 5632) { W = Wv; WT = wqkvT + 1280 * 1024; N = 256;  loc = bx - 5376; nbx = 8; }
    else                { W = Wo; WT = woT;                 N = 1024; loc = bx - 5632; nbx = 32; }
    const int n0 = (loc % nbx) * 32, k0 = (loc / nbx) * 32;
    const int tx = t & 31, ty = t >> 5;
#pragma unroll
    for (int i = 0; i < 4; ++i)
      ftile[ty + 8 * i][tx] = W[(size_t)(k0 + ty + 8 * i) * N + n0 + tx];
    __syncthreads();
#pragma unroll
    for (int i = 0; i < 4; ++i)
      WT[(size_t)(n0 + ty + 8 * i) * 1024 + k0 + tx] = f2bf(ftile[tx][ty + 8 * i]);
    return;
  }
  // spec scan block
  const int wv = t >> 6, l = t & 63;
#pragma unroll
  for (int i = 0; i < 16; ++i) {
    const int b = wv * 16 + i;
    const u64 m = __ballot(spec[b * 64 + l] != 0);
    if (l == 0) { smask[b] = m; scnt_s[b] = __popcll(m); }
  }
  __syncthreads();
  if (wv == 0) {
    const int v = scnt_s[l];
    int inc = v;
#pragma unroll
    for (int d = 1; d < 64; d <<= 1) {
      const int o = __shfl_up(inc, d);
      if (l >= d) inc += o;
    }
    spref[l] = inc - v;  // exclusive prefix
    if (l == 63) scnt[0] = inc;
    spb[l] = smask[l];
  }
  __syncthreads();
#pragma unroll
  for (int i = 0; i < 16; ++i) {
    const int b = wv * 16 + i;
    const u64 m = smask[b];
    if ((m >> l) & 1ull)
      sidx[spref[b] + __popcll(m & ((1ull << l) - 1ull))] = b * 64 + l;
  }
  if (t < 64) {
    const int e = eosi[t * 64];
    const int tlo = e >> 6;
    const int nsp = spref[tlo];
    const int nspt = (nsp + 63) >> 6;
    qmeta[t] = make_int4(tlo, nspt, nspt + (t - tlo + 1), nsp);
  }
}

// ---------------- pack: special K rows + special V^T cols (from Vtg) ----------------
__global__ __launch_bounds__(256)
void pack_kernel(const u16* __restrict__ Kb, const u16* __restrict__ Vtg,
                 const int* __restrict__ sidx, const int* __restrict__ scnt,
                 u16* __restrict__ Kg, u16* __restrict__ Vgt) {
  __shared__ int rowidx[64];
  const int nspec = scnt[0];
  const int j0 = (int)blockIdx.x * 64;
  if (j0 >= nspec) return;
  const int kvh = (int)blockIdx.y;
  const int t = (int)threadIdx.x;
  if (t < 64) rowidx[t] = (j0 + t < nspec) ? sidx[j0 + t] : 0;
  __syncthreads();
  {
    const int r = t >> 2;
    const int s = rowidx[r];
    const int j = j0 + r;
    const u16* srcrow = Kb + (size_t)s * 256 + kvh * 64;
    u16* dstrow = Kg + (size_t)j * 256 + kvh * 64;
    const int x = (j ^ s) & 7;
#pragma unroll
    for (int a = 0; a < 2; ++a) {
      const int cd = (t & 3) * 2 + a;
      *(s16x8*)(dstrow + cd * 8) = *(const s16x8*)(srcrow + ((cd ^ x) * 8));
    }
  }
  {
    const int d = t >> 2;
    const u16* srcrow = Vtg + (size_t)(kvh * 64 + d) * 4096;
    u16* drow = Vgt + (size_t)(kvh * 64 + d) * 4096 + j0;
    const int xd = (d & 7) << 3;
#pragma unroll
    for (int a = 0; a < 2; ++a) {
      const int jc = (t & 3) * 2 + a;
      s16x8 o;
#pragma unroll
      for (int e = 0; e < 8; ++e) {
        const int s = rowidx[jc * 8 + e];
        o[e] = (short)srcrow[(s & ~63) + ((s & 63) ^ xd)];
      }
      *(s16x8*)(drow + ((jc * 8) ^ xd)) = o;
    }
  }
}

// ---------------- 128x64 MFMA GEMM core, K=1024, 4 waves of 32x64 ----------------
// MODE 0: C fp32 out.  MODE 1: QKV, RoPE fused; K swizzled; V written transposed to Vtg.
template <int MODE>
__global__ __launch_bounds__(256, 3)
void gemm128(const u16* __restrict__ A, const u16* __restrict__ BT,
             const float* __restrict__ cosp, const float* __restrict__ sinp,
             u16* __restrict__ Qb, u16* __restrict__ Kb, u16* __restrict__ Vtg,
             float* __restrict__ Cf) {
  __shared__ __align__(16) u16 As[128 * 32];
  __shared__ __align__(16) u16 Bs[64 * 32];
  const int t = (int)threadIdx.x;
  const int w = t >> 6;
  const int lane = t & 63;
  const int lr = lane & 15, lg = lane >> 4;

  // XCD-chunked swizzle: consecutive virtual ids share the A-panel and sit on
  // one XCD -> A re-reads hit that XCD's L2 instead of L3.
  const int nx = (int)gridDim.x;
  const int nwg = nx * (int)gridDim.y;
  const int id = xcd_swz((int)blockIdx.x + (int)blockIdx.y * nx, nwg);
  const int m0 = (id / nx) * 128;
  const int n0 = (id % nx) * 64;
  const int wm = w * 32;

  f32x4 acc[2][4] = {};

  const int srow = t >> 2;
  const int scol = (t & 3) * 8;

  for (int k0 = 0; k0 < 1024; k0 += 32) {
    gload16(A + (size_t)(m0 + srow) * 1024 + k0 + scol, As + t * 8);
    gload16(A + (size_t)(m0 + 64 + srow) * 1024 + k0 + scol, As + 2048 + t * 8);
    gload16(BT + (size_t)(n0 + srow) * 1024 + k0 + scol, Bs + t * 8);
    __syncthreads();
    bf16x8 af[2], bg[4];
#pragma unroll
    for (int mi = 0; mi < 2; ++mi)
      af[mi] = *(const bf16x8*)(As + (wm + mi * 16 + lr) * 32 + lg * 8);
#pragma unroll
    for (int ni = 0; ni < 4; ++ni)
      bg[ni] = *(const bf16x8*)(Bs + (ni * 16 + lr) * 32 + lg * 8);
#pragma unroll
    for (int mi = 0; mi < 2; ++mi)
#pragma unroll
      for (int ni = 0; ni < 4; ++ni)
        acc[mi][ni] = mfma16(af[mi], bg[ni], acc[mi][ni]);
    __syncthreads();
  }

  if (MODE == 0) {
#pragma unroll
    for (int mi = 0; mi < 2; ++mi)
#pragma unroll
      for (int r = 0; r < 4; ++r) {
        const int m = m0 + wm + mi * 16 + lg * 4 + r;
#pragma unroll
        for (int ni = 0; ni < 4; ++ni)
          Cf[(size_t)m * 1024 + n0 + ni * 16 + lr] = acc[mi][ni][r];
      }
  } else if (n0 < 1280) {
    // RoPE (Q or K): pair (d, d+32) = (acc[mi][ni], acc[mi][ni+2])
#pragma unroll
    for (int mi = 0; mi < 2; ++mi)
#pragma unroll
      for (int r = 0; r < 4; ++r) {
        const int m = m0 + wm + mi * 16 + lg * 4 + r;
        const float* cr = cosp + (size_t)m * 64;
        const float* sr = sinp + (size_t)m * 64;
        float o[4];
#pragma unroll
        for (int ni = 0; ni < 2; ++ni) {
          const int d1 = ni * 16 + lr, d2 = d1 + 32;
          const float x = acc[mi][ni][r], y = acc[mi][ni + 2][r];
          o[ni]     = x * cr[d1] - y * sr[d1];
          o[ni + 2] = y * cr[d2] + x * sr[d2];
        }
        if (n0 < 1024) {
          u16* dst = Qb + (size_t)m * 1024 + n0;
#pragma unroll
          for (int ni = 0; ni < 4; ++ni) dst[ni * 16 + lr] = f2bf(o[ni]);
        } else {
          u16* dst = Kb + (size_t)m * 256 + (n0 - 1024);
          const int sw = (m & 7) << 3;
#pragma unroll
          for (int ni = 0; ni < 4; ++ni) dst[(ni * 16 + lr) ^ sw] = f2bf(o[ni]);
        }
      }
  } else {
    // V: write transposed + chunk-swizzled directly into Vtg[kvh*64+d][s]
    const int kvh = (n0 - 1280) >> 6;
#pragma unroll
    for (int ni = 0; ni < 4; ++ni) {
      const int d = ni * 16 + lr;
      u16* vrow = Vtg + (size_t)(kvh * 64 + d) * 4096;
      const int xd = (d & 7) << 3;
#pragma unroll
      for (int mi = 0; mi < 2; ++mi) {
        const int sb = m0 + wm + mi * 16 + lg * 4;
        const int os = (sb & ~63) | ((sb & 63) ^ xd);
        uint2 pkv;
        pkv.x = (u32)f2bf(acc[mi][ni][0]) | ((u32)f2bf(acc[mi][ni][1]) << 16);
        pkv.y = (u32)f2bf(acc[mi][ni][2]) | ((u32)f2bf(acc[mi][ni][3]) << 16);
        *(uint2*)(vrow + os) = pkv;
      }
    }
  }
}

// ---------------- flash attention, sentence-sparse, local-first ----------------
// grid (64 q-tiles, 16 heads) XCD-swizzled, 256 threads = 4 waves x 16 q-rows
__global__ __launch_bounds__(256, 5)
void attn_kernel(const u16* __restrict__ Qb, const u16* __restrict__ Kb,
                 const u16* __restrict__ Vtg, const u16* __restrict__ Kg,
                 const u16* __restrict__ Vgt, const u64* __restrict__ spb,
                 const int* __restrict__ eosi, const int4* __restrict__ qmeta,
                 u16* __restrict__ Ob) {
  __shared__ __align__(16) u16 lds[2][2][4096];

  const int id = xcd_swz((int)blockIdx.x + (int)blockIdx.y * 64, 1024);
  const int qt = 63 - (id & 63);
  const int h = id >> 6;
  const int kvh = h >> 2;
  const int t = (int)threadIdx.x;
  const int w = t >> 6;
  const int lane = t & 63;
  const int lr = lane & 15, lg = lane >> 4;
  const int q0 = qt * 64;
  const int q = q0 + w * 16 + lr;
  const int swl = (lr & 7) << 3;

  const int4 qm = qmeta[qt];       // {tile_lo, nspt, nit, nsp}
  const int tile_lo = qm.x;
  const int nit = qm.z;
  const int nsp = qm.w;
  const int nloc = qt - tile_lo + 1;

  bf16x8 aq[2];
  {
    const u16* qp = Qb + (size_t)q * 1024 + h * 64 + lg * 8;
    aq[0] = *(const bf16x8*)qp;
    aq[1] = *(const bf16x8*)(qp + 32);
  }
  const int eos_q = eosi[q];

  f32x4 acc[4] = {};
  float mrow = -3.0e38f;
  float lrow = 0.0f;

  const int grow = t >> 3;
  const int gcol = (t & 7) * 8;

  auto STAGE = [&](int buf, int it) {
    const u16 *kp, *vp;
    if (it < nloc) {
      const int kbase = (tile_lo + it) * 64;
      kp = Kb + (size_t)kbase * 256 + kvh * 64;
      vp = Vtg + (size_t)(kvh * 64) * 4096 + kbase;
    } else {
      const int jb = (it - nloc) * 64;
      kp = Kg + (size_t)jb * 256 + kvh * 64;
      vp = Vgt + (size_t)(kvh * 64) * 4096 + jb;
    }
#pragma unroll
    for (int i = 0; i < 2; ++i) {
      gload16(kp + (size_t)(i * 32 + grow) * 256 + gcol, &lds[buf][0][i * 2048 + t * 8]);
      gload16(vp + (size_t)(i * 32 + grow) * 4096 + gcol, &lds[buf][1][i * 2048 + t * 8]);
    }
  };

  STAGE(0, 0);
  __syncthreads();

  for (int it = 0; it < nit; ++it) {
    if (it + 1 < nit) STAGE((it + 1) & 1, it + 1);
    const u16* Kl = &lds[it & 1][0][0];
    const u16* Vl = &lds[it & 1][1][0];

    f32x4 st[4];
#pragma unroll
    for (int kt = 0; kt < 4; ++kt) {
      f32x4 s = {};
#pragma unroll
      for (int c = 0; c < 2; ++c) {
        bf16x8 ak = *(const bf16x8*)(Kl + (kt * 16 + lr) * 64 + ((c * 32 + lg * 8) ^ swl));
        s = mfma16(ak, aq[c], s);
      }
      st[kt] = s;
    }

    u64 allowed;
    if (it < nloc) {
      const int kbase = (tile_lo + it) * 64;
      const u64 spec = spb[tile_lo + it];
      const int dq = q - kbase;
      const u64 causal = (dq >= 63) ? ~0ull : ((2ull << dq) - 1ull);
      const int de = eos_q - kbase;
      const u64 ge = (de <= 0) ? ~0ull : (de >= 64 ? 0ull : (~0ull << de));
      allowed = causal & (ge | spec);
    } else {
      const int rem = nsp - (it - nloc) * 64;
      allowed = (rem >= 64) ? ~0ull : ((1ull << rem) - 1ull);
    }

    float xs[16];
    float tmax = -3.0e38f;
#pragma unroll
    for (int kt = 0; kt < 4; ++kt) {
      const u32 bits = (u32)(allowed >> (kt * 16 + lg * 4)) & 0xFu;
#pragma unroll
      for (int r = 0; r < 4; ++r) {
        const float x = ((bits >> r) & 1u) ? st[kt][r] * 0.18033688011112042f : -3.0e38f;
        xs[kt * 4 + r] = x;
        tmax = fmaxf(tmax, x);
      }
    }
    tmax = fmaxf(tmax, __shfl_xor(tmax, 16));
    tmax = fmaxf(tmax, __shfl_xor(tmax, 32));
    const float mn = fmaxf(mrow, tmax);
    const float resc = exp2f(mrow - mn);
    mrow = mn;

    float rs = 0.0f;
    u32 pk[8];
#pragma unroll
    for (int i = 0; i < 16; i += 2) {
      const float p0 = exp2f(xs[i] - mn);
      const float p1 = exp2f(xs[i + 1] - mn);
      rs += p0 + p1;
      pk[i >> 1] = (u32)f2bf(p0) | ((u32)f2bf(p1) << 16);
    }
    rs += __shfl_xor(rs, 16);
    rs += __shfl_xor(rs, 32);
    lrow = lrow * resc + rs;

#pragma unroll
    for (int dt = 0; dt < 4; ++dt)
#pragma unroll
      for (int r = 0; r < 4; ++r) acc[dt][r] *= resc;

#pragma unroll
    for (int kt = 0; kt < 4; ++kt) {
      union { u32 u[2]; s16x4 v; } cv;
      cv.u[0] = pk[kt * 2]; cv.u[1] = pk[kt * 2 + 1];
      const int vo = (kt * 16 + lg * 4) ^ swl;
#pragma unroll
      for (int dt = 0; dt < 4; ++dt) {
        s16x4 av = *(const s16x4*)(Vl + (dt * 16 + lr) * 64 + vo);
        acc[dt] = mfma16x16(av, cv.v, acc[dt]);
      }
    }
    __syncthreads();
  }

  const float inv = 1.0f / lrow;
#pragma unroll
  for (int dt = 0; dt < 4; ++dt) {
    const u32 w0 = (u32)f2bf(acc[dt][0] * inv) | ((u32)f2bf(acc[dt][1] * inv) << 16);
    const u32 w1 = (u32)f2bf(acc[dt][2] * inv) | ((u32)f2bf(acc[dt][3] * inv) << 16);
    u32* dst = (u32*)(Ob + (size_t)q * 1024 + h * 64 + dt * 16 + lg * 4);
    dst[0] = w0; dst[1] = w1;
  }
}

// ---------------- launch ----------------
extern "C" void kernel_launch(void* const* d_in, const int* in_sizes, int n_in,
                              void* d_out, int out_size, void* d_ws, size_t ws_size,
                              hipStream_t stream) {
  (void)in_sizes; (void)n_in; (void)out_size; (void)ws_size;
  const float* hidden = (const float*)d_in[0];
  const float* cosp   = (const float*)d_in[1];
  const float* sinp   = (const float*)d_in[2];
  const float* Wq     = (const float*)d_in[3];
  const float* Wk     = (const float*)d_in[4];
  const float* Wv     = (const float*)d_in[5];
  const float* Wo     = (const float*)d_in[6];
  const int* spec     = (const int*)d_in[7];
  const int* eosi     = (const int*)d_in[8];
  float* out = (float*)d_out;

  u16* ws = (u16*)d_ws;
  u16* hbf   = ws;                       // 4096*1024, reused after QKV gemm
  u16* wqkvT = hbf + 4194304;            // 1536*1024
  u16* woT   = wqkvT + 1572864;          // 1024*1024
  u16* Qb    = woT + 1048576;            // 4096*1024
  u16* Kb    = Qb + 4194304;             // 4096*256 (chunk-swizzled by row)
  u16* Vtg   = Kb + 1048576;             // 4*64*4096 transposed V (written by gemm<1>)
  u16* Ob    = Vtg + 1048576;            // 4096*1024
  u16* tail  = Ob + 4194304;             // spec metadata
  u64* spb   = (u64*)tail;               // 64 x u64
  int* sidx  = (int*)(tail + 256);       // 4096 int
  int* scnt  = (int*)(tail + 8448);      // 1 int
  int4* qmeta = (int4*)(tail + 8512);    // 64 x int4
  // aliased onto hbf after gemm<1> has consumed it:
  u16* Kg    = hbf;                      // 4096*256 packed special K
  u16* Vgt   = hbf + 1048576;            // 4*64*4096 packed special V^T

  prep_kernel<<<dim3(6657), dim3(256), 0, stream>>>(hidden, Wq, Wk, Wv, Wo, spec, eosi,
                                                    hbf, wqkvT, woT, spb, sidx, scnt, qmeta);
  gemm128<1><<<dim3(24, 32), dim3(256), 0, stream>>>(hbf, wqkvT, cosp, sinp,
                                                     Qb, Kb, Vtg, nullptr);
  pack_kernel<<<dim3(64, 4), dim3(256), 0, stream>>>(Kb, Vtg, sidx, scnt, Kg, Vgt);
  attn_kernel<<<dim3(64, 16), dim3(256), 0, stream>>>(Qb, Kb, Vtg, Kg, Vgt, spb,
                                                      eosi, qmeta, Ob);
  gemm128<0><<<dim3(16, 32), dim3(256), 0, stream>>>(Ob, woT, nullptr, nullptr,
                                                     nullptr, nullptr, nullptr, out);
}

// Round 7
// 82.034 us; speedup vs baseline: 4.1306x; 1.0980x over previous
//
#include <hip/hip_runtime.h>

typedef __bf16 bf16x8 __attribute__((ext_vector_type(8)));
typedef float f32x4 __attribute__((ext_vector_type(4)));
typedef short s16x8 __attribute__((ext_vector_type(8)));
typedef short s16x4 __attribute__((ext_vector_type(4)));
typedef unsigned short u16;
typedef unsigned int u32;
typedef unsigned long long u64;

#define S_LEN 4096
#define DMODEL 1024
#define NH 16
#define HD 64

static __device__ __forceinline__ u16 f2bf(float f) {
  union { float f; u32 u; } a; a.f = f;
  u32 r = (a.u + 0x7fffu + ((a.u >> 16) & 1u)) >> 16;
  return (u16)r;
}

static __device__ __forceinline__ f32x4 mfma16(bf16x8 a, bf16x8 b, f32x4 c) {
  return __builtin_amdgcn_mfma_f32_16x16x32_bf16(a, b, c, 0, 0, 0);
}

static __device__ __forceinline__ f32x4 mfma16x16(s16x4 a, s16x4 b, f32x4 c) {
#if __has_builtin(__builtin_amdgcn_mfma_f32_16x16x16bf16_1k)
  return __builtin_amdgcn_mfma_f32_16x16x16bf16_1k(a, b, c, 0, 0, 0);
#else
  asm("v_mfma_f32_16x16x16_bf16 %0, %1, %2, %0" : "+v"(c) : "v"(a), "v"(b));
  return c;
#endif
}

static __device__ __forceinline__ void gload16(const void* g, void* l) {
  __builtin_amdgcn_global_load_lds((const __attribute__((address_space(1))) u32*)g,
                                   (__attribute__((address_space(3))) u32*)l, 16, 0, 0);
}

// bijective chunked XCD swizzle (requires nwg % 8 == 0)
static __device__ __forceinline__ int xcd_swz(int id, int nwg) {
  return (id & 7) * (nwg >> 3) + (id >> 3);
}

// ---------------- fused prep: cast + 4 weight transposes + spec scan ----------------
__global__ __launch_bounds__(256)
void prep_kernel(const float* __restrict__ hidden, const float* __restrict__ Wq,
                 const float* __restrict__ Wk, const float* __restrict__ Wv,
                 const float* __restrict__ Wo, const int* __restrict__ spec,
                 const int* __restrict__ eosi,
                 u16* __restrict__ hbf, u16* __restrict__ wqkvT, u16* __restrict__ woT,
                 u64* __restrict__ spb, int* __restrict__ sidx, int* __restrict__ scnt,
                 int4* __restrict__ qmeta) {
  __shared__ float ftile[32][33];
  __shared__ u64 smask[64];
  __shared__ int scnt_s[64];
  __shared__ int spref[64];

  const int bx = (int)blockIdx.x;
  const int t = (int)threadIdx.x;

  if (bx < 4096) {  // cast
    const int i = (bx * 256 + t) * 4;
    const float4 v = *(const float4*)(hidden + i);
    uint2 o;
    o.x = (u32)f2bf(v.x) | ((u32)f2bf(v.y) << 16);
    o.y = (u32)f2bf(v.z) | ((u32)f2bf(v.w) << 16);
    *(uint2*)(hbf + i) = o;
    return;
  }
  if (bx < 6656) {  // weight transposes
    const float* W; u16* WT; int N, loc, nbx;
    if (bx < 5120)      { W = Wq; WT = wqkvT;               N = 1024; loc = bx - 4096; nbx = 32; }
    else if (bx < 5376) { W = Wk; WT = wqkvT + 1024 * 1024; N = 256;  loc = bx - 5120; nbx = 8; }
    else if (bx < 5632) { W = Wv; WT = wqkvT + 1280 * 1024; N = 256;  loc = bx - 5376; nbx = 8; }
    else                { W = Wo; WT = woT;                 N = 1024; loc = bx - 5632; nbx = 32; }
    const int n0 = (loc % nbx) * 32, k0 = (loc / nbx) * 32;
    const int tx = t & 31, ty = t >> 5;
#pragma unroll
    for (int i = 0; i < 4; ++i)
      ftile[ty + 8 * i][tx] = W[(size_t)(k0 + ty + 8 * i) * N + n0 + tx];
    __syncthreads();
#pragma unroll
    for (int i = 0; i < 4; ++i)
      WT[(size_t)(n0 + ty + 8 * i) * 1024 + k0 + tx] = f2bf(ftile[tx][ty + 8 * i]);
    return;
  }
  // spec scan block
  const int wv = t >> 6, l = t & 63;
#pragma unroll
  for (int i = 0; i < 16; ++i) {
    const int b = wv * 16 + i;
    const u64 m = __ballot(spec[b * 64 + l] != 0);
    if (l == 0) { smask[b] = m; scnt_s[b] = __popcll(m); }
  }
  __syncthreads();
  if (wv == 0) {
    const int v = scnt_s[l];
    int inc = v;
#pragma unroll
    for (int d = 1; d < 64; d <<= 1) {
      const int o = __shfl_up(inc, d);
      if (l >= d) inc += o;
    }
    spref[l] = inc - v;  // exclusive prefix
    if (l == 63) scnt[0] = inc;
    spb[l] = smask[l];
  }
  __syncthreads();
#pragma unroll
  for (int i = 0; i < 16; ++i) {
    const int b = wv * 16 + i;
    const u64 m = smask[b];
    if ((m >> l) & 1ull)
      sidx[spref[b] + __popcll(m & ((1ull << l) - 1ull))] = b * 64 + l;
  }
  if (t < 64) {
    const int e = eosi[t * 64];
    const int tlo = e >> 6;
    const int nsp = spref[tlo];
    const int nspt = (nsp + 63) >> 6;
    qmeta[t] = make_int4(tlo, nspt, nspt + (t - tlo + 1), nsp);
  }
}

// ---------------- pack: special K rows + special V^T cols (from Vtg) ----------------
__global__ __launch_bounds__(256)
void pack_kernel(const u16* __restrict__ Kb, const u16* __restrict__ Vtg,
                 const int* __restrict__ sidx, const int* __restrict__ scnt,
                 u16* __restrict__ Kg, u16* __restrict__ Vgt) {
  __shared__ int rowidx[64];
  const int nspec = scnt[0];
  const int j0 = (int)blockIdx.x * 64;
  if (j0 >= nspec) return;
  const int kvh = (int)blockIdx.y;
  const int t = (int)threadIdx.x;
  if (t < 64) rowidx[t] = (j0 + t < nspec) ? sidx[j0 + t] : 0;
  __syncthreads();
  {
    const int r = t >> 2;
    const int s = rowidx[r];
    const int j = j0 + r;
    const u16* srcrow = Kb + (size_t)s * 256 + kvh * 64;
    u16* dstrow = Kg + (size_t)j * 256 + kvh * 64;
    const int x = (j ^ s) & 7;
#pragma unroll
    for (int a = 0; a < 2; ++a) {
      const int cd = (t & 3) * 2 + a;
      *(s16x8*)(dstrow + cd * 8) = *(const s16x8*)(srcrow + ((cd ^ x) * 8));
    }
  }
  {
    const int d = t >> 2;
    const u16* srcrow = Vtg + (size_t)(kvh * 64 + d) * 4096;
    u16* drow = Vgt + (size_t)(kvh * 64 + d) * 4096 + j0;
    const int xd = (d & 7) << 3;
#pragma unroll
    for (int a = 0; a < 2; ++a) {
      const int jc = (t & 3) * 2 + a;
      s16x8 o;
#pragma unroll
      for (int e = 0; e < 8; ++e) {
        const int s = rowidx[jc * 8 + e];
        o[e] = (short)srcrow[(s & ~63) + ((s & 63) ^ xd)];
      }
      *(s16x8*)(drow + ((jc * 8) ^ xd)) = o;
    }
  }
}

// ---------------- 128x64 MFMA GEMM, BK=64, double-buffered, LDS-swizzled ----------------
// MODE 0: C fp32 out.  MODE 1: QKV, RoPE fused; K swizzled; V written transposed to Vtg.
template <int MODE>
__global__ __launch_bounds__(256, 3)
void gemm128(const u16* __restrict__ A, const u16* __restrict__ BT,
             const float* __restrict__ cosp, const float* __restrict__ sinp,
             u16* __restrict__ Qb, u16* __restrict__ Kb, u16* __restrict__ Vtg,
             float* __restrict__ Cf) {
  __shared__ __align__(16) u16 As[2][128 * 64];
  __shared__ __align__(16) u16 Bs[2][64 * 64];
  const int t = (int)threadIdx.x;
  const int w = t >> 6;
  const int lane = t & 63;
  const int lr = lane & 15, lg = lane >> 4;

  const int nx = (int)gridDim.x;
  const int nwg = nx * (int)gridDim.y;
  const int id = xcd_swz((int)blockIdx.x + (int)blockIdx.y * nx, nwg);
  const int m0 = (id / nx) * 128;
  const int n0 = (id % nx) * 64;
  const int wm = w * 32;

  f32x4 acc[2][4] = {};

  const int srow = t >> 3;   // 0..31 (per 32-row pass)
  const int sp = t & 7;      // dest 16B chunk within 128B row

  // staging: linear LDS dest (lane-ordered), source chunk pre-swizzled p^(row&7)
  auto STAGE = [&](int buf, int k0) {
#pragma unroll
    for (int i = 0; i < 4; ++i) {
      const int j = i * 32 + srow;
      gload16(A + (size_t)(m0 + j) * 1024 + k0 + ((sp ^ (j & 7)) * 8),
              &As[buf][i * 2048 + t * 8]);
    }
#pragma unroll
    for (int i = 0; i < 2; ++i) {
      const int j = i * 32 + srow;
      gload16(BT + (size_t)(n0 + j) * 1024 + k0 + ((sp ^ (j & 7)) * 8),
              &Bs[buf][i * 2048 + t * 8]);
    }
  };

  STAGE(0, 0);
  __syncthreads();

  for (int it = 0; it < 16; ++it) {
    const int cur = it & 1;
    if (it + 1 < 16) STAGE(cur ^ 1, (it + 1) * 64);
#pragma unroll
    for (int c = 0; c < 2; ++c) {   // k ascending: bit-identical accumulation
      bf16x8 af[2], bg[4];
#pragma unroll
      for (int mi = 0; mi < 2; ++mi) {
        const int row = wm + mi * 16 + lr;
        af[mi] = *(const bf16x8*)&As[cur][row * 64 + (((c * 4 + lg) ^ (row & 7)) * 8)];
      }
#pragma unroll
      for (int ni = 0; ni < 4; ++ni) {
        const int row = ni * 16 + lr;
        bg[ni] = *(const bf16x8*)&Bs[cur][row * 64 + (((c * 4 + lg) ^ (row & 7)) * 8)];
      }
#pragma unroll
      for (int mi = 0; mi < 2; ++mi)
#pragma unroll
        for (int ni = 0; ni < 4; ++ni)
          acc[mi][ni] = mfma16(af[mi], bg[ni], acc[mi][ni]);
    }
    __syncthreads();
  }

  if (MODE == 0) {
#pragma unroll
    for (int mi = 0; mi < 2; ++mi)
#pragma unroll
      for (int r = 0; r < 4; ++r) {
        const int m = m0 + wm + mi * 16 + lg * 4 + r;
#pragma unroll
        for (int ni = 0; ni < 4; ++ni)
          Cf[(size_t)m * 1024 + n0 + ni * 16 + lr] = acc[mi][ni][r];
      }
  } else if (n0 < 1280) {
    // RoPE (Q or K): pair (d, d+32) = (acc[mi][ni], acc[mi][ni+2])
#pragma unroll
    for (int mi = 0; mi < 2; ++mi)
#pragma unroll
      for (int r = 0; r < 4; ++r) {
        const int m = m0 + wm + mi * 16 + lg * 4 + r;
        const float* cr = cosp + (size_t)m * 64;
        const float* sr = sinp + (size_t)m * 64;
        float o[4];
#pragma unroll
        for (int ni = 0; ni < 2; ++ni) {
          const int d1 = ni * 16 + lr, d2 = d1 + 32;
          const float x = acc[mi][ni][r], y = acc[mi][ni + 2][r];
          o[ni]     = x * cr[d1] - y * sr[d1];
          o[ni + 2] = y * cr[d2] + x * sr[d2];
        }
        if (n0 < 1024) {
          u16* dst = Qb + (size_t)m * 1024 + n0;
#pragma unroll
          for (int ni = 0; ni < 4; ++ni) dst[ni * 16 + lr] = f2bf(o[ni]);
        } else {
          u16* dst = Kb + (size_t)m * 256 + (n0 - 1024);
          const int sw = (m & 7) << 3;
#pragma unroll
          for (int ni = 0; ni < 4; ++ni) dst[(ni * 16 + lr) ^ sw] = f2bf(o[ni]);
        }
      }
  } else {
    // V: write transposed + chunk-swizzled directly into Vtg[kvh*64+d][s]
    const int kvh = (n0 - 1280) >> 6;
#pragma unroll
    for (int ni = 0; ni < 4; ++ni) {
      const int d = ni * 16 + lr;
      u16* vrow = Vtg + (size_t)(kvh * 64 + d) * 4096;
      const int xd = (d & 7) << 3;
#pragma unroll
      for (int mi = 0; mi < 2; ++mi) {
        const int sb = m0 + wm + mi * 16 + lg * 4;
        const int os = (sb & ~63) | ((sb & 63) ^ xd);
        uint2 pkv;
        pkv.x = (u32)f2bf(acc[mi][ni][0]) | ((u32)f2bf(acc[mi][ni][1]) << 16);
        pkv.y = (u32)f2bf(acc[mi][ni][2]) | ((u32)f2bf(acc[mi][ni][3]) << 16);
        *(uint2*)(vrow + os) = pkv;
      }
    }
  }
}

// ---------------- flash attention, sentence-sparse, local-first ----------------
// grid (64 q-tiles, 16 heads) XCD-swizzled, 256 threads = 4 waves x 16 q-rows
__global__ __launch_bounds__(256, 5)
void attn_kernel(const u16* __restrict__ Qb, const u16* __restrict__ Kb,
                 const u16* __restrict__ Vtg, const u16* __restrict__ Kg,
                 const u16* __restrict__ Vgt, const u64* __restrict__ spb,
                 const int* __restrict__ eosi, const int4* __restrict__ qmeta,
                 u16* __restrict__ Ob) {
  __shared__ __align__(16) u16 lds[2][2][4096];

  const int id = xcd_swz((int)blockIdx.x + (int)blockIdx.y * 64, 1024);
  const int qt = 63 - (id & 63);
  const int h = id >> 6;
  const int kvh = h >> 2;
  const int t = (int)threadIdx.x;
  const int w = t >> 6;
  const int lane = t & 63;
  const int lr = lane & 15, lg = lane >> 4;
  const int q0 = qt * 64;
  const int q = q0 + w * 16 + lr;
  const int swl = (lr & 7) << 3;

  const int4 qm = qmeta[qt];       // {tile_lo, nspt, nit, nsp}
  const int tile_lo = qm.x;
  const int nit = qm.z;
  const int nsp = qm.w;
  const int nloc = qt - tile_lo + 1;

  bf16x8 aq[2];
  {
    const u16* qp = Qb + (size_t)q * 1024 + h * 64 + lg * 8;
    aq[0] = *(const bf16x8*)qp;
    aq[1] = *(const bf16x8*)(qp + 32);
  }
  const int eos_q = eosi[q];

  f32x4 acc[4] = {};
  float mrow = -3.0e38f;
  float lrow = 0.0f;

  const int grow = t >> 3;
  const int gcol = (t & 7) * 8;

  auto STAGE = [&](int buf, int it) {
    const u16 *kp, *vp;
    if (it < nloc) {
      const int kbase = (tile_lo + it) * 64;
      kp = Kb + (size_t)kbase * 256 + kvh * 64;
      vp = Vtg + (size_t)(kvh * 64) * 4096 + kbase;
    } else {
      const int jb = (it - nloc) * 64;
      kp = Kg + (size_t)jb * 256 + kvh * 64;
      vp = Vgt + (size_t)(kvh * 64) * 4096 + jb;
    }
#pragma unroll
    for (int i = 0; i < 2; ++i) {
      gload16(kp + (size_t)(i * 32 + grow) * 256 + gcol, &lds[buf][0][i * 2048 + t * 8]);
      gload16(vp + (size_t)(i * 32 + grow) * 4096 + gcol, &lds[buf][1][i * 2048 + t * 8]);
    }
  };

  STAGE(0, 0);
  __syncthreads();

  for (int it = 0; it < nit; ++it) {
    if (it + 1 < nit) STAGE((it + 1) & 1, it + 1);
    const u16* Kl = &lds[it & 1][0][0];
    const u16* Vl = &lds[it & 1][1][0];

    f32x4 st[4];
#pragma unroll
    for (int kt = 0; kt < 4; ++kt) {
      f32x4 s = {};
#pragma unroll
      for (int c = 0; c < 2; ++c) {
        bf16x8 ak = *(const bf16x8*)(Kl + (kt * 16 + lr) * 64 + ((c * 32 + lg * 8) ^ swl));
        s = mfma16(ak, aq[c], s);
      }
      st[kt] = s;
    }

    u64 allowed;
    if (it < nloc) {
      const int kbase = (tile_lo + it) * 64;
      const u64 spec = spb[tile_lo + it];
      const int dq = q - kbase;
      const u64 causal = (dq >= 63) ? ~0ull : ((2ull << dq) - 1ull);
      const int de = eos_q - kbase;
      const u64 ge = (de <= 0) ? ~0ull : (de >= 64 ? 0ull : (~0ull << de));
      allowed = causal & (ge | spec);
    } else {
      const int rem = nsp - (it - nloc) * 64;
      allowed = (rem >= 64) ? ~0ull : ((1ull << rem) - 1ull);
    }

    float xs[16];
    float tmax = -3.0e38f;
#pragma unroll
    for (int kt = 0; kt < 4; ++kt) {
      const u32 bits = (u32)(allowed >> (kt * 16 + lg * 4)) & 0xFu;
#pragma unroll
      for (int r = 0; r < 4; ++r) {
        const float x = ((bits >> r) & 1u) ? st[kt][r] * 0.18033688011112042f : -3.0e38f;
        xs[kt * 4 + r] = x;
        tmax = fmaxf(tmax, x);
      }
    }
    tmax = fmaxf(tmax, __shfl_xor(tmax, 16));
    tmax = fmaxf(tmax, __shfl_xor(tmax, 32));
    const float mn = fmaxf(mrow, tmax);
    const float resc = exp2f(mrow - mn);
    mrow = mn;

    float rs = 0.0f;
    u32 pk[8];
#pragma unroll
    for (int i = 0; i < 16; i += 2) {
      const float p0 = exp2f(xs[i] - mn);
      const float p1 = exp2f(xs[i + 1] - mn);
      rs += p0 + p1;
      pk[i >> 1] = (u32)f2bf(p0) | ((u32)f2bf(p1) << 16);
    }
    rs += __shfl_xor(rs, 16);
    rs += __shfl_xor(rs, 32);
    lrow = lrow * resc + rs;

#pragma unroll
    for (int dt = 0; dt < 4; ++dt)
#pragma unroll
      for (int r = 0; r < 4; ++r) acc[dt][r] *= resc;

#pragma unroll
    for (int kt = 0; kt < 4; ++kt) {
      union { u32 u[2]; s16x4 v; } cv;
      cv.u[0] = pk[kt * 2]; cv.u[1] = pk[kt * 2 + 1];
      const int vo = (kt * 16 + lg * 4) ^ swl;
#pragma unroll
      for (int dt = 0; dt < 4; ++dt) {
        s16x4 av = *(const s16x4*)(Vl + (dt * 16 + lr) * 64 + vo);
        acc[dt] = mfma16x16(av, cv.v, acc[dt]);
      }
    }
    __syncthreads();
  }

  const float inv = 1.0f / lrow;
#pragma unroll
  for (int dt = 0; dt < 4; ++dt) {
    const u32 w0 = (u32)f2bf(acc[dt][0] * inv) | ((u32)f2bf(acc[dt][1] * inv) << 16);
    const u32 w1 = (u32)f2bf(acc[dt][2] * inv) | ((u32)f2bf(acc[dt][3] * inv) << 16);
    u32* dst = (u32*)(Ob + (size_t)q * 1024 + h * 64 + dt * 16 + lg * 4);
    dst[0] = w0; dst[1] = w1;
  }
}

// ---------------- launch ----------------
extern "C" void kernel_launch(void* const* d_in, const int* in_sizes, int n_in,
                              void* d_out, int out_size, void* d_ws, size_t ws_size,
                              hipStream_t stream) {
  (void)in_sizes; (void)n_in; (void)out_size; (void)ws_size;
  const float* hidden = (const float*)d_in[0];
  const float* cosp   = (const float*)d_in[1];
  const float* sinp   = (const float*)d_in[2];
  const float* Wq     = (const float*)d_in[3];
  const float* Wk     = (const float*)d_in[4];
  const float* Wv     = (const float*)d_in[5];
  const float* Wo     = (const float*)d_in[6];
  const int* spec     = (const int*)d_in[7];
  const int* eosi     = (const int*)d_in[8];
  float* out = (float*)d_out;

  u16* ws = (u16*)d_ws;
  u16* hbf   = ws;                       // 4096*1024, reused after QKV gemm
  u16* wqkvT = hbf + 4194304;            // 1536*1024
  u16* woT   = wqkvT + 1572864;          // 1024*1024
  u16* Qb    = woT + 1048576;            // 4096*1024
  u16* Kb    = Qb + 4194304;             // 4096*256 (chunk-swizzled by row)
  u16* Vtg   = Kb + 1048576;             // 4*64*4096 transposed V (written by gemm<1>)
  u16* Ob    = Vtg + 1048576;            // 4096*1024
  u16* tail  = Ob + 4194304;             // spec metadata
  u64* spb   = (u64*)tail;               // 64 x u64
  int* sidx  = (int*)(tail + 256);       // 4096 int
  int* scnt  = (int*)(tail + 8448);      // 1 int
  int4* qmeta = (int4*)(tail + 8512);    // 64 x int4
  // aliased onto hbf after gemm<1> has consumed it:
  u16* Kg    = hbf;                      // 4096*256 packed special K
  u16* Vgt   = hbf + 1048576;            // 4*64*4096 packed special V^T

  prep_kernel<<<dim3(6657), dim3(256), 0, stream>>>(hidden, Wq, Wk, Wv, Wo, spec, eosi,
                                                    hbf, wqkvT, woT, spb, sidx, scnt, qmeta);
  gemm128<1><<<dim3(24, 32), dim3(256), 0, stream>>>(hbf, wqkvT, cosp, sinp,
                                                     Qb, Kb, Vtg, nullptr);
  pack_kernel<<<dim3(64, 4), dim3(256), 0, stream>>>(Kb, Vtg, sidx, scnt, Kg, Vgt);
  attn_kernel<<<dim3(64, 16), dim3(256), 0, stream>>>(Qb, Kb, Vtg, Kg, Vgt, spb,
                                                      eosi, qmeta, Ob);
  gemm128<0><<<dim3(16, 32), dim3(256), 0, stream>>>(Ob, woT, nullptr, nullptr,
                                                     nullptr, nullptr, nullptr, out);
}

// Round 8
// 79.523 us; speedup vs baseline: 4.2610x; 1.0316x over previous
//
#include <hip/hip_runtime.h>

typedef __bf16 bf16x8 __attribute__((ext_vector_type(8)));
typedef float f32x4 __attribute__((ext_vector_type(4)));
typedef short s16x8 __attribute__((ext_vector_type(8)));
typedef short s16x4 __attribute__((ext_vector_type(4)));
typedef unsigned short u16;
typedef unsigned int u32;
typedef unsigned long long u64;

#define S_LEN 4096
#define DMODEL 1024
#define NH 16
#define HD 64

static __device__ __forceinline__ u16 f2bf(float f) {
  union { float f; u32 u; } a; a.f = f;
  u32 r = (a.u + 0x7fffu + ((a.u >> 16) & 1u)) >> 16;
  return (u16)r;
}

static __device__ __forceinline__ f32x4 mfma16(bf16x8 a, bf16x8 b, f32x4 c) {
  return __builtin_amdgcn_mfma_f32_16x16x32_bf16(a, b, c, 0, 0, 0);
}

static __device__ __forceinline__ f32x4 mfma16x16(s16x4 a, s16x4 b, f32x4 c) {
#if __has_builtin(__builtin_amdgcn_mfma_f32_16x16x16bf16_1k)
  return __builtin_amdgcn_mfma_f32_16x16x16bf16_1k(a, b, c, 0, 0, 0);
#else
  asm("v_mfma_f32_16x16x16_bf16 %0, %1, %2, %0" : "+v"(c) : "v"(a), "v"(b));
  return c;
#endif
}

static __device__ __forceinline__ void gload16(const void* g, void* l) {
  __builtin_amdgcn_global_load_lds((const __attribute__((address_space(1))) u32*)g,
                                   (__attribute__((address_space(3))) u32*)l, 16, 0, 0);
}

// counted-vmcnt barrier pair: loads issued for the NEXT tile stay in flight
// across the barrier (only the CURRENT tile's loads are waited on).
#define WAIT_VM(N) asm volatile("s_waitcnt vmcnt(" #N ")" ::: "memory")
static __device__ __forceinline__ void sbar() { __builtin_amdgcn_s_barrier(); }
static __device__ __forceinline__ void spin() { __builtin_amdgcn_sched_barrier(0); }

// bijective chunked XCD swizzle (requires nwg % 8 == 0)
static __device__ __forceinline__ int xcd_swz(int id, int nwg) {
  return (id & 7) * (nwg >> 3) + (id >> 3);
}

// ---------------- fused prep: cast + 4 weight transposes + spec scan ----------------
__global__ __launch_bounds__(256)
void prep_kernel(const float* __restrict__ hidden, const float* __restrict__ Wq,
                 const float* __restrict__ Wk, const float* __restrict__ Wv,
                 const float* __restrict__ Wo, const int* __restrict__ spec,
                 const int* __restrict__ eosi,
                 u16* __restrict__ hbf, u16* __restrict__ wqkvT, u16* __restrict__ woT,
                 u64* __restrict__ spb, int* __restrict__ sidx, int* __restrict__ scnt,
                 int4* __restrict__ qmeta) {
  __shared__ float ftile[32][33];
  __shared__ u64 smask[64];
  __shared__ int scnt_s[64];
  __shared__ int spref[64];

  const int bx = (int)blockIdx.x;
  const int t = (int)threadIdx.x;

  if (bx < 4096) {  // cast
    const int i = (bx * 256 + t) * 4;
    const float4 v = *(const float4*)(hidden + i);
    uint2 o;
    o.x = (u32)f2bf(v.x) | ((u32)f2bf(v.y) << 16);
    o.y = (u32)f2bf(v.z) | ((u32)f2bf(v.w) << 16);
    *(uint2*)(hbf + i) = o;
    return;
  }
  if (bx < 6656) {  // weight transposes
    const float* W; u16* WT; int N, loc, nbx;
    if (bx < 5120)      { W = Wq; WT = wqkvT;               N = 1024; loc = bx - 4096; nbx = 32; }
    else if (bx < 5376) { W = Wk; WT = wqkvT + 1024 * 1024; N = 256;  loc = bx - 5120; nbx = 8; }
    else if (bx < 5632) { W = Wv; WT = wqkvT + 1280 * 1024; N = 256;  loc = bx - 5376; nbx = 8; }
    else                { W = Wo; WT = woT;                 N = 1024; loc = bx - 5632; nbx = 32; }
    const int n0 = (loc % nbx) * 32, k0 = (loc / nbx) * 32;
    const int tx = t & 31, ty = t >> 5;
#pragma unroll
    for (int i = 0; i < 4; ++i)
      ftile[ty + 8 * i][tx] = W[(size_t)(k0 + ty + 8 * i) * N + n0 + tx];
    __syncthreads();
#pragma unroll
    for (int i = 0; i < 4; ++i)
      WT[(size_t)(n0 + ty + 8 * i) * 1024 + k0 + tx] = f2bf(ftile[tx][ty + 8 * i]);
    return;
  }
  // spec scan block
  const int wv = t >> 6, l = t & 63;
#pragma unroll
  for (int i = 0; i < 16; ++i) {
    const int b = wv * 16 + i;
    const u64 m = __ballot(spec[b * 64 + l] != 0);
    if (l == 0) { smask[b] = m; scnt_s[b] = __popcll(m); }
  }
  __syncthreads();
  if (wv == 0) {
    const int v = scnt_s[l];
    int inc = v;
#pragma unroll
    for (int d = 1; d < 64; d <<= 1) {
      const int o = __shfl_up(inc, d);
      if (l >= d) inc += o;
    }
    spref[l] = inc - v;  // exclusive prefix
    if (l == 63) scnt[0] = inc;
    spb[l] = smask[l];
  }
  __syncthreads();
#pragma unroll
  for (int i = 0; i < 16; ++i) {
    const int b = wv * 16 + i;
    const u64 m = smask[b];
    if ((m >> l) & 1ull)
      sidx[spref[b] + __popcll(m & ((1ull << l) - 1ull))] = b * 64 + l;
  }
  if (t < 64) {
    const int e = eosi[t * 64];
    const int tlo = e >> 6;
    const int nsp = spref[tlo];
    const int nspt = (nsp + 63) >> 6;
    qmeta[t] = make_int4(tlo, nspt, nspt + (t - tlo + 1), nsp);
  }
}

// ---------------- pack: special K rows + special V^T cols (from Vtg) ----------------
__global__ __launch_bounds__(256)
void pack_kernel(const u16* __restrict__ Kb, const u16* __restrict__ Vtg,
                 const int* __restrict__ sidx, const int* __restrict__ scnt,
                 u16* __restrict__ Kg, u16* __restrict__ Vgt) {
  __shared__ int rowidx[64];
  const int nspec = scnt[0];
  const int j0 = (int)blockIdx.x * 64;
  if (j0 >= nspec) return;
  const int kvh = (int)blockIdx.y;
  const int t = (int)threadIdx.x;
  if (t < 64) rowidx[t] = (j0 + t < nspec) ? sidx[j0 + t] : 0;
  __syncthreads();
  {
    const int r = t >> 2;
    const int s = rowidx[r];
    const int j = j0 + r;
    const u16* srcrow = Kb + (size_t)s * 256 + kvh * 64;
    u16* dstrow = Kg + (size_t)j * 256 + kvh * 64;
    const int x = (j ^ s) & 7;
#pragma unroll
    for (int a = 0; a < 2; ++a) {
      const int cd = (t & 3) * 2 + a;
      *(s16x8*)(dstrow + cd * 8) = *(const s16x8*)(srcrow + ((cd ^ x) * 8));
    }
  }
  {
    const int d = t >> 2;
    const u16* srcrow = Vtg + (size_t)(kvh * 64 + d) * 4096;
    u16* drow = Vgt + (size_t)(kvh * 64 + d) * 4096 + j0;
    const int xd = (d & 7) << 3;
#pragma unroll
    for (int a = 0; a < 2; ++a) {
      const int jc = (t & 3) * 2 + a;
      s16x8 o;
#pragma unroll
      for (int e = 0; e < 8; ++e) {
        const int s = rowidx[jc * 8 + e];
        o[e] = (short)srcrow[(s & ~63) + ((s & 63) ^ xd)];
      }
      *(s16x8*)(drow + ((jc * 8) ^ xd)) = o;
    }
  }
}

// ---------------- 128x64 MFMA GEMM, BK=64, dbuf + counted-vmcnt pipeline ----------------
// MODE 0: C fp32 out.  MODE 1: QKV, RoPE fused; K swizzled; V written transposed to Vtg.
template <int MODE>
__global__ __launch_bounds__(256, 3)
void gemm128(const u16* __restrict__ A, const u16* __restrict__ BT,
             const float* __restrict__ cosp, const float* __restrict__ sinp,
             u16* __restrict__ Qb, u16* __restrict__ Kb, u16* __restrict__ Vtg,
             float* __restrict__ Cf) {
  __shared__ __align__(16) u16 As[2][128 * 64];
  __shared__ __align__(16) u16 Bs[2][64 * 64];
  const int t = (int)threadIdx.x;
  const int w = t >> 6;
  const int lane = t & 63;
  const int lr = lane & 15, lg = lane >> 4;

  const int nx = (int)gridDim.x;
  const int nwg = nx * (int)gridDim.y;
  const int id = xcd_swz((int)blockIdx.x + (int)blockIdx.y * nx, nwg);
  const int m0 = (id / nx) * 128;
  const int n0 = (id % nx) * 64;
  const int wm = w * 32;

  f32x4 acc[2][4] = {};

  const int srow = t >> 3;   // 0..31 (per 32-row pass)
  const int sp = t & 7;      // dest 16B chunk within 128B row

  // staging: linear LDS dest (lane-ordered), source chunk pre-swizzled p^(row&7)
  auto STAGE = [&](int buf, int k0) {  // 6 gload16 per thread
#pragma unroll
    for (int i = 0; i < 4; ++i) {
      const int j = i * 32 + srow;
      gload16(A + (size_t)(m0 + j) * 1024 + k0 + ((sp ^ (j & 7)) * 8),
              &As[buf][i * 2048 + t * 8]);
    }
#pragma unroll
    for (int i = 0; i < 2; ++i) {
      const int j = i * 32 + srow;
      gload16(BT + (size_t)(n0 + j) * 1024 + k0 + ((sp ^ (j & 7)) * 8),
              &Bs[buf][i * 2048 + t * 8]);
    }
  };

  STAGE(0, 0);

  for (int it = 0; it < 16; ++it) {
    const int cur = it & 1;
    if (it < 15) {
      STAGE(cur ^ 1, (it + 1) * 64);  // 6 next-tile loads stay in flight
      WAIT_VM(6);                     // only current tile's 6 loads complete
    } else {
      WAIT_VM(0);
    }
    spin();
    sbar();                           // raw barrier: no vmcnt(0) drain
#pragma unroll
    for (int c = 0; c < 2; ++c) {     // k ascending: bit-identical accumulation
      bf16x8 af[2], bg[4];
#pragma unroll
      for (int mi = 0; mi < 2; ++mi) {
        const int row = wm + mi * 16 + lr;
        af[mi] = *(const bf16x8*)&As[cur][row * 64 + (((c * 4 + lg) ^ (row & 7)) * 8)];
      }
#pragma unroll
      for (int ni = 0; ni < 4; ++ni) {
        const int row = ni * 16 + lr;
        bg[ni] = *(const bf16x8*)&Bs[cur][row * 64 + (((c * 4 + lg) ^ (row & 7)) * 8)];
      }
#pragma unroll
      for (int mi = 0; mi < 2; ++mi)
#pragma unroll
        for (int ni = 0; ni < 4; ++ni)
          acc[mi][ni] = mfma16(af[mi], bg[ni], acc[mi][ni]);
    }
    spin();
    sbar();                           // protect cur buffer before next STAGE overwrites
  }

  if (MODE == 0) {
#pragma unroll
    for (int mi = 0; mi < 2; ++mi)
#pragma unroll
      for (int r = 0; r < 4; ++r) {
        const int m = m0 + wm + mi * 16 + lg * 4 + r;
#pragma unroll
        for (int ni = 0; ni < 4; ++ni)
          Cf[(size_t)m * 1024 + n0 + ni * 16 + lr] = acc[mi][ni][r];
      }
  } else if (n0 < 1280) {
    // RoPE (Q or K): pair (d, d+32) = (acc[mi][ni], acc[mi][ni+2])
#pragma unroll
    for (int mi = 0; mi < 2; ++mi)
#pragma unroll
      for (int r = 0; r < 4; ++r) {
        const int m = m0 + wm + mi * 16 + lg * 4 + r;
        const float* cr = cosp + (size_t)m * 64;
        const float* sr = sinp + (size_t)m * 64;
        float o[4];
#pragma unroll
        for (int ni = 0; ni < 2; ++ni) {
          const int d1 = ni * 16 + lr, d2 = d1 + 32;
          const float x = acc[mi][ni][r], y = acc[mi][ni + 2][r];
          o[ni]     = x * cr[d1] - y * sr[d1];
          o[ni + 2] = y * cr[d2] + x * sr[d2];
        }
        if (n0 < 1024) {
          u16* dst = Qb + (size_t)m * 1024 + n0;
#pragma unroll
          for (int ni = 0; ni < 4; ++ni) dst[ni * 16 + lr] = f2bf(o[ni]);
        } else {
          u16* dst = Kb + (size_t)m * 256 + (n0 - 1024);
          const int sw = (m & 7) << 3;
#pragma unroll
          for (int ni = 0; ni < 4; ++ni) dst[(ni * 16 + lr) ^ sw] = f2bf(o[ni]);
        }
      }
  } else {
    // V: write transposed + chunk-swizzled directly into Vtg[kvh*64+d][s]
    const int kvh = (n0 - 1280) >> 6;
#pragma unroll
    for (int ni = 0; ni < 4; ++ni) {
      const int d = ni * 16 + lr;
      u16* vrow = Vtg + (size_t)(kvh * 64 + d) * 4096;
      const int xd = (d & 7) << 3;
#pragma unroll
      for (int mi = 0; mi < 2; ++mi) {
        const int sb = m0 + wm + mi * 16 + lg * 4;
        const int os = (sb & ~63) | ((sb & 63) ^ xd);
        uint2 pkv;
        pkv.x = (u32)f2bf(acc[mi][ni][0]) | ((u32)f2bf(acc[mi][ni][1]) << 16);
        pkv.y = (u32)f2bf(acc[mi][ni][2]) | ((u32)f2bf(acc[mi][ni][3]) << 16);
        *(uint2*)(vrow + os) = pkv;
      }
    }
  }
}

// ---------------- flash attention, sentence-sparse, counted-vmcnt pipeline ----------------
// grid (64 q-tiles, 16 heads) XCD-swizzled, 256 threads = 4 waves x 16 q-rows
__global__ __launch_bounds__(256, 5)
void attn_kernel(const u16* __restrict__ Qb, const u16* __restrict__ Kb,
                 const u16* __restrict__ Vtg, const u16* __restrict__ Kg,
                 const u16* __restrict__ Vgt, const u64* __restrict__ spb,
                 const int* __restrict__ eosi, const int4* __restrict__ qmeta,
                 u16* __restrict__ Ob) {
  __shared__ __align__(16) u16 lds[2][2][4096];

  const int id = xcd_swz((int)blockIdx.x + (int)blockIdx.y * 64, 1024);
  const int qt = 63 - (id & 63);
  const int h = id >> 6;
  const int kvh = h >> 2;
  const int t = (int)threadIdx.x;
  const int w = t >> 6;
  const int lane = t & 63;
  const int lr = lane & 15, lg = lane >> 4;
  const int q0 = qt * 64;
  const int q = q0 + w * 16 + lr;
  const int swl = (lr & 7) << 3;

  const int4 qm = qmeta[qt];       // {tile_lo, nspt, nit, nsp}
  const int tile_lo = qm.x;
  const int nit = qm.z;
  const int nsp = qm.w;
  const int nloc = qt - tile_lo + 1;

  bf16x8 aq[2];
  {
    const u16* qp = Qb + (size_t)q * 1024 + h * 64 + lg * 8;
    aq[0] = *(const bf16x8*)qp;
    aq[1] = *(const bf16x8*)(qp + 32);
  }
  const int eos_q = eosi[q];

  f32x4 acc[4] = {};
  float mrow = -3.0e38f;
  float lrow = 0.0f;

  const int grow = t >> 3;
  const int gcol = (t & 7) * 8;

  auto STAGE = [&](int buf, int it) {  // 4 gload16 per thread
    const u16 *kp, *vp;
    if (it < nloc) {
      const int kbase = (tile_lo + it) * 64;
      kp = Kb + (size_t)kbase * 256 + kvh * 64;
      vp = Vtg + (size_t)(kvh * 64) * 4096 + kbase;
    } else {
      const int jb = (it - nloc) * 64;
      kp = Kg + (size_t)jb * 256 + kvh * 64;
      vp = Vgt + (size_t)(kvh * 64) * 4096 + jb;
    }
#pragma unroll
    for (int i = 0; i < 2; ++i) {
      gload16(kp + (size_t)(i * 32 + grow) * 256 + gcol, &lds[buf][0][i * 2048 + t * 8]);
      gload16(vp + (size_t)(i * 32 + grow) * 4096 + gcol, &lds[buf][1][i * 2048 + t * 8]);
    }
  };

  STAGE(0, 0);

  for (int it = 0; it < nit; ++it) {
    if (it + 1 < nit) {
      STAGE((it + 1) & 1, it + 1);   // next-tile loads stay in flight
      WAIT_VM(4);
    } else {
      WAIT_VM(0);
    }
    spin();
    sbar();
    const u16* Kl = &lds[it & 1][0][0];
    const u16* Vl = &lds[it & 1][1][0];

    f32x4 st[4];
#pragma unroll
    for (int kt = 0; kt < 4; ++kt) {
      f32x4 s = {};
#pragma unroll
      for (int c = 0; c < 2; ++c) {
        bf16x8 ak = *(const bf16x8*)(Kl + (kt * 16 + lr) * 64 + ((c * 32 + lg * 8) ^ swl));
        s = mfma16(ak, aq[c], s);
      }
      st[kt] = s;
    }

    u64 allowed;
    if (it < nloc) {
      const int kbase = (tile_lo + it) * 64;
      const u64 spec = spb[tile_lo + it];
      const int dq = q - kbase;
      const u64 causal = (dq >= 63) ? ~0ull : ((2ull << dq) - 1ull);
      const int de = eos_q - kbase;
      const u64 ge = (de <= 0) ? ~0ull : (de >= 64 ? 0ull : (~0ull << de));
      allowed = causal & (ge | spec);
    } else {
      const int rem = nsp - (it - nloc) * 64;
      allowed = (rem >= 64) ? ~0ull : ((1ull << rem) - 1ull);
    }

    float xs[16];
    float tmax = -3.0e38f;
#pragma unroll
    for (int kt = 0; kt < 4; ++kt) {
      const u32 bits = (u32)(allowed >> (kt * 16 + lg * 4)) & 0xFu;
#pragma unroll
      for (int r = 0; r < 4; ++r) {
        const float x = ((bits >> r) & 1u) ? st[kt][r] * 0.18033688011112042f : -3.0e38f;
        xs[kt * 4 + r] = x;
        tmax = fmaxf(tmax, x);
      }
    }
    tmax = fmaxf(tmax, __shfl_xor(tmax, 16));
    tmax = fmaxf(tmax, __shfl_xor(tmax, 32));
    const float mn = fmaxf(mrow, tmax);
    const float resc = exp2f(mrow - mn);
    mrow = mn;

    float rs = 0.0f;
    u32 pk[8];
#pragma unroll
    for (int i = 0; i < 16; i += 2) {
      const float p0 = exp2f(xs[i] - mn);
      const float p1 = exp2f(xs[i + 1] - mn);
      rs += p0 + p1;
      pk[i >> 1] = (u32)f2bf(p0) | ((u32)f2bf(p1) << 16);
    }
    rs += __shfl_xor(rs, 16);
    rs += __shfl_xor(rs, 32);
    lrow = lrow * resc + rs;

#pragma unroll
    for (int dt = 0; dt < 4; ++dt)
#pragma unroll
      for (int r = 0; r < 4; ++r) acc[dt][r] *= resc;

#pragma unroll
    for (int kt = 0; kt < 4; ++kt) {
      union { u32 u[2]; s16x4 v; } cv;
      cv.u[0] = pk[kt * 2]; cv.u[1] = pk[kt * 2 + 1];
      const int vo = (kt * 16 + lg * 4) ^ swl;
#pragma unroll
      for (int dt = 0; dt < 4; ++dt) {
        s16x4 av = *(const s16x4*)(Vl + (dt * 16 + lr) * 64 + vo);
        acc[dt] = mfma16x16(av, cv.v, acc[dt]);
      }
    }
    spin();
    sbar();
  }

  const float inv = 1.0f / lrow;
#pragma unroll
  for (int dt = 0; dt < 4; ++dt) {
    const u32 w0 = (u32)f2bf(acc[dt][0] * inv) | ((u32)f2bf(acc[dt][1] * inv) << 16);
    const u32 w1 = (u32)f2bf(acc[dt][2] * inv) | ((u32)f2bf(acc[dt][3] * inv) << 16);
    u32* dst = (u32*)(Ob + (size_t)q * 1024 + h * 64 + dt * 16 + lg * 4);
    dst[0] = w0; dst[1] = w1;
  }
}

// ---------------- launch ----------------
extern "C" void kernel_launch(void* const* d_in, const int* in_sizes, int n_in,
                              void* d_out, int out_size, void* d_ws, size_t ws_size,
                              hipStream_t stream) {
  (void)in_sizes; (void)n_in; (void)out_size; (void)ws_size;
  const float* hidden = (const float*)d_in[0];
  const float* cosp   = (const float*)d_in[1];
  const float* sinp   = (const float*)d_in[2];
  const float* Wq     = (const float*)d_in[3];
  const float* Wk     = (const float*)d_in[4];
  const float* Wv     = (const float*)d_in[5];
  const float* Wo     = (const float*)d_in[6];
  const int* spec     = (const int*)d_in[7];
  const int* eosi     = (const int*)d_in[8];
  float* out = (float*)d_out;

  u16* ws = (u16*)d_ws;
  u16* hbf   = ws;                       // 4096*1024, reused after QKV gemm
  u16* wqkvT = hbf + 4194304;            // 1536*1024
  u16* woT   = wqkvT + 1572864;          // 1024*1024
  u16* Qb    = woT + 1048576;            // 4096*1024
  u16* Kb    = Qb + 4194304;             // 4096*256 (chunk-swizzled by row)
  u16* Vtg   = Kb + 1048576;             // 4*64*4096 transposed V (written by gemm<1>)
  u16* Ob    = Vtg + 1048576;            // 4096*1024
  u16* tail  = Ob + 4194304;             // spec metadata
  u64* spb   = (u64*)tail;               // 64 x u64
  int* sidx  = (int*)(tail + 256);       // 4096 int
  int* scnt  = (int*)(tail + 8448);      // 1 int
  int4* qmeta = (int4*)(tail + 8512);    // 64 x int4
  // aliased onto hbf after gemm<1> has consumed it:
  u16* Kg    = hbf;                      // 4096*256 packed special K
  u16* Vgt   = hbf + 1048576;            // 4*64*4096 packed special V^T

  prep_kernel<<<dim3(6657), dim3(256), 0, stream>>>(hidden, Wq, Wk, Wv, Wo, spec, eosi,
                                                    hbf, wqkvT, woT, spb, sidx, scnt, qmeta);
  gemm128<1><<<dim3(24, 32), dim3(256), 0, stream>>>(hbf, wqkvT, cosp, sinp,
                                                     Qb, Kb, Vtg, nullptr);
  pack_kernel<<<dim3(64, 4), dim3(256), 0, stream>>>(Kb, Vtg, sidx, scnt, Kg, Vgt);
  attn_kernel<<<dim3(64, 16), dim3(256), 0, stream>>>(Qb, Kb, Vtg, Kg, Vgt, spb,
                                                      eosi, qmeta, Ob);
  gemm128<0><<<dim3(16, 32), dim3(256), 0, stream>>>(Ob, woT, nullptr, nullptr,
                                                     nullptr, nullptr, nullptr, out);
}